// Round 9
// baseline (262.904 us; speedup 1.0000x reference)
//
#include <hip/hip_runtime.h>
#include <math.h>

#define HID 64
#define BKT_SHIFT 13                 // 8192 nodes per bucket
#define BKT_RANGE 8192
#define CCHUNK 32                    // wave-chunks per bucket in phase B

typedef __attribute__((ext_vector_type(8))) short short8;
typedef __attribute__((ext_vector_type(4))) float f32x4;
typedef unsigned long long ull;

union FragU {
    uint4 q;
    short8 v;
    uint32_t u[4];
};

__device__ __forceinline__ uint32_t cvt_pk_bf16(float lo, float hi) {
    uint32_t r;
    asm("v_cvt_pk_bf16_f32 %0, %1, %2" : "=v"(r) : "v"(lo), "v"(hi));
    return r;
}
__device__ __forceinline__ float bf16lo_f(uint32_t u) { return __uint_as_float(u << 16); }
__device__ __forceinline__ float bf16hi_f(uint32_t u) { return __uint_as_float(u & 0xFFFF0000u); }
__device__ __forceinline__ unsigned short bf16_of(float v) {
    return (unsigned short)(cvt_pk_bf16(v, 0.f) & 0xFFFFu);
}

// ---------------------------------------------------------------------------
// Prep: bf16-transposed weights (identical to round 7/8).
// ---------------------------------------------------------------------------
__global__ void prep_kernel(
    const float* __restrict__ w1,  const float* __restrict__ b1,  const float* __restrict__ w2,
    const float* __restrict__ nw1, const float* __restrict__ nb1, const float* __restrict__ nw2,
    const float* __restrict__ mw1, const float* __restrict__ mb1, const float* __restrict__ mw2,
    unsigned short* __restrict__ w1x,  unsigned short* __restrict__ w2T,
    unsigned short* __restrict__ nw1x, unsigned short* __restrict__ nw2T,
    unsigned short* __restrict__ mw1x, unsigned short* __restrict__ mw2T)
{
    int t = blockIdx.x * 256 + threadIdx.x;
    if (t < 4096) {
        int j = t >> 6, k = t & 63;
        w2T [t] = bf16_of(w2 [k * HID + j]);
        nw2T[t] = bf16_of(nw2[k * HID + j]);
        mw2T[t] = bf16_of(mw2[k * HID + j]);
    }
    if (t < 512) {
        int j = t >> 3, k = t & 7;
        float ve = k == 0 ? w1[j] : k == 1 ? w1[HID + j] : k == 2 ? w1[2 * HID + j] : k == 3 ? b1[j] : 0.f;
        float vn = k == 0 ? nw1[j] : k == 1 ? nw1[HID + j] : k == 2 ? nb1[j] : 0.f;
        float vm = k == 0 ? mw1[j] : k == 1 ? mb1[j] : 0.f;
        w1x [t] = bf16_of(ve);
        nw1x[t] = bf16_of(vn);
        mw1x[t] = bf16_of(vm);
    }
}

// ---------------------------------------------------------------------------
// Edge v5: persistent + pipelined, 2-phase set processing with HALF the LDS
// (16 KB/block) so 6 blocks/CU fit (launch_bounds(256,6), grid 1536):
// 3x the resident waves of round 8 to hide bpermute/LDS/MFMA latency.
// Epilogue uses 4 independent accumulator chains (latency fix).
// ---------------------------------------------------------------------------
__global__ __launch_bounds__(256, 6) void edge_mfma4_kernel(
    const float* __restrict__ nf, const float* __restrict__ ef,
    const int* __restrict__ src, const int* __restrict__ dst,
    const unsigned short* __restrict__ w1x, const unsigned short* __restrict__ w2T,
    const float* __restrict__ b2, const float* __restrict__ w3, const float* __restrict__ b3,
    uint2* __restrict__ recs, ull* __restrict__ offs,
    float* __restrict__ aggFb, int E, int B, int nbatch, int mode)
{
    __shared__ uint2 tile[4][2][16][16];   // [wave][set-in-phase][row][chunk] = 16 KB

    const int tid  = threadIdx.x;
    const int lane = tid & 63;
    const int wid  = tid >> 6;
    const int g    = lane >> 4;
    const int eL   = lane & 15;

    // ---- weights: once per block ----
    FragU af1[4];
#pragma unroll
    for (int t = 0; t < 4; ++t) {
        uint4 q = *(const uint4*)&w1x[(t * 16 + eL) * 8];
        af1[t].q = (g == 0) ? q : make_uint4(0, 0, 0, 0);
    }
    FragU af2[4][2];
#pragma unroll
    for (int t = 0; t < 4; ++t)
#pragma unroll
        for (int h = 0; h < 2; ++h)
            af2[t][h].q = *(const uint4*)&w2T[(t * 16 + eL) * 64 + h * 32 + g * 8];

    f32x4 b2v4[4];
    uint32_t w3p[8];
#pragma unroll
    for (int t = 0; t < 4; ++t) {
        int j = t * 16 + g * 4;
        b2v4[t] = *(const f32x4*)&b2[j];
        f32x4 wv = *(const f32x4*)&w3[j];
        w3p[2 * t]     = cvt_pk_bf16(wv[0], wv[1]);
        w3p[2 * t + 1] = cvt_pk_bf16(wv[2], wv[3]);
    }
    const float b3c = b3[0];

    // ---- first batch loads ----
    int bi   = blockIdx.x;
    if (bi >= nbatch) return;
    int eidx = bi * 256 + tid;
    int ei   = eidx < E ? eidx : E - 1;
    int dcur = dst[ei];
    float a  = nf[src[ei]];
    float b  = nf[dcur];
    float c  = ef[ei];

    for (;;) {
        // ---- prefetch next batch indices (issued early, consumed late) ----
        const int nbi   = bi + gridDim.x;
        const bool hn   = nbi < nbatch;
        const int neidx = hn ? nbi * 256 + tid : eidx;
        const int nei   = neidx < E ? neidx : E - 1;
        const int ns    = src[nei];
        const int nd    = dst[nei];
        const float ncf = ef[nei];

        float na = 0.f, nb = 0.f;
        float mymsg = 0.f;

#pragma unroll
        for (int ph = 0; ph < 2; ++ph) {
            // ---- L1 phase for sets 2ph, 2ph+1 ----
#pragma unroll
            for (int ss = 0; ss < 2; ++ss) {
                const int s = 2 * ph + ss;
                float av = __shfl(a, s * 16 + eL);
                float bv = __shfl(b, s * 16 + eL);
                float cv = __shfl(c, s * 16 + eL);
                FragU bin;
                bin.u[0] = (g == 0) ? cvt_pk_bf16(av, bv) : 0u;
                bin.u[1] = (g == 0) ? cvt_pk_bf16(cv, 1.0f) : 0u;
                bin.u[2] = 0u; bin.u[3] = 0u;
#pragma unroll
                for (int t = 0; t < 4; ++t) {
                    f32x4 h4 = __builtin_amdgcn_mfma_f32_16x16x32_bf16(
                        af1[t].v, bin.v, (f32x4){0.f, 0.f, 0.f, 0.f}, 0, 0, 0);
                    uint32_t p0 = cvt_pk_bf16(fmaxf(h4[0], 0.f), fmaxf(h4[1], 0.f));
                    uint32_t p1 = cvt_pk_bf16(fmaxf(h4[2], 0.f), fmaxf(h4[3], 0.f));
                    tile[wid][ss][eL][(4 * t + g) ^ ((eL & 7) << 1)] = make_uint2(p0, p1);
                }
            }

            // ---- gathers for next batch: issue once, hidden under L2+phase1 ----
            if (ph == 0) {
                na = nf[ns];
                nb = nf[nd];
            }

            // ---- L2 phase for sets 2ph, 2ph+1 ----
#pragma unroll
            for (int ss = 0; ss < 2; ++ss) {
                const int s = 2 * ph + ss;
                const uint4* row = (const uint4*)&tile[wid][ss][eL][0];
                FragU bf0, bf1;
                bf0.q = row[(g)     ^ (eL & 7)];
                bf1.q = row[(4 + g) ^ (eL & 7)];

                float q0, q1, q2, q3;
                {
                    f32x4 ac = __builtin_amdgcn_mfma_f32_16x16x32_bf16(af2[0][0].v, bf0.v, b2v4[0], 0, 0, 0);
                    ac = __builtin_amdgcn_mfma_f32_16x16x32_bf16(af2[0][1].v, bf1.v, ac, 0, 0, 0);
                    q0 = fmaxf(ac[0], 0.f) * bf16lo_f(w3p[0]);
                    q0 = fmaf(fmaxf(ac[1], 0.f), bf16hi_f(w3p[0]), q0);
                    q0 = fmaf(fmaxf(ac[2], 0.f), bf16lo_f(w3p[1]), q0);
                    q0 = fmaf(fmaxf(ac[3], 0.f), bf16hi_f(w3p[1]), q0);
                }
                {
                    f32x4 ac = __builtin_amdgcn_mfma_f32_16x16x32_bf16(af2[1][0].v, bf0.v, b2v4[1], 0, 0, 0);
                    ac = __builtin_amdgcn_mfma_f32_16x16x32_bf16(af2[1][1].v, bf1.v, ac, 0, 0, 0);
                    q1 = fmaxf(ac[0], 0.f) * bf16lo_f(w3p[2]);
                    q1 = fmaf(fmaxf(ac[1], 0.f), bf16hi_f(w3p[2]), q1);
                    q1 = fmaf(fmaxf(ac[2], 0.f), bf16lo_f(w3p[3]), q1);
                    q1 = fmaf(fmaxf(ac[3], 0.f), bf16hi_f(w3p[3]), q1);
                }
                {
                    f32x4 ac = __builtin_amdgcn_mfma_f32_16x16x32_bf16(af2[2][0].v, bf0.v, b2v4[2], 0, 0, 0);
                    ac = __builtin_amdgcn_mfma_f32_16x16x32_bf16(af2[2][1].v, bf1.v, ac, 0, 0, 0);
                    q2 = fmaxf(ac[0], 0.f) * bf16lo_f(w3p[4]);
                    q2 = fmaf(fmaxf(ac[1], 0.f), bf16hi_f(w3p[4]), q2);
                    q2 = fmaf(fmaxf(ac[2], 0.f), bf16lo_f(w3p[5]), q2);
                    q2 = fmaf(fmaxf(ac[3], 0.f), bf16hi_f(w3p[5]), q2);
                }
                {
                    f32x4 ac = __builtin_amdgcn_mfma_f32_16x16x32_bf16(af2[3][0].v, bf0.v, b2v4[3], 0, 0, 0);
                    ac = __builtin_amdgcn_mfma_f32_16x16x32_bf16(af2[3][1].v, bf1.v, ac, 0, 0, 0);
                    q3 = fmaxf(ac[0], 0.f) * bf16lo_f(w3p[6]);
                    q3 = fmaf(fmaxf(ac[1], 0.f), bf16hi_f(w3p[6]), q3);
                    q3 = fmaf(fmaxf(ac[2], 0.f), bf16lo_f(w3p[7]), q3);
                    q3 = fmaf(fmaxf(ac[3], 0.f), bf16hi_f(w3p[7]), q3);
                }
                float p = (q0 + q1) + (q2 + q3);
                p += __shfl_xor(p, 16);
                p += __shfl_xor(p, 32);
                if (s == g) mymsg = p + b3c;
            }
        }

        const bool valid = eidx < E;

        if (mode == 1) {
            if (valid) atomicAdd(&aggFb[dcur], mymsg);
        } else {
            // ---- bucket append: coalesced wave-private, zero atomics ----
            const int bkt = dcur >> BKT_SHIFT;
            const ull lt = (1ull << lane) - 1;
            int myslot = 0;
            int off = 0;
            uint32_t pack_lo = 0, pack_hi = 0;
            for (int bb = 0; bb < B; ++bb) {
                if (bb < 4) pack_lo |= (uint32_t)off << (8 * bb);
                else        pack_hi |= (uint32_t)off << (8 * (bb - 4));
                ull m = __ballot(valid && bkt == bb);
                if (valid && bkt == bb) myslot = off + (int)__popcll(m & lt);
                off += (int)__popcll(m);
            }
            pack_hi |= (uint32_t)off << 24;

            const size_t wgl = (size_t)bi * 4 + wid;
            if (valid) recs[wgl * 64 + myslot] = make_uint2((uint32_t)dcur, __float_as_uint(mymsg));
            if (lane == 0) offs[wgl] = ((ull)pack_hi << 32) | (ull)pack_lo;
        }

        if (!hn) break;
        bi = nbi; eidx = neidx; ei = nei;
        a = na; b = nb; c = ncf; dcur = nd;
    }
}

// ---------------------------------------------------------------------------
// Phase B: block (b,c) accumulates bucket b's records from wave-chunk c into
// a 32KB LDS array (LDS atomics), then writes a dense partial plane.
// ---------------------------------------------------------------------------
__global__ __launch_bounds__(256) void bucket_accum_kernel(
    const uint2* __restrict__ recs, const ull* __restrict__ offs,
    float* __restrict__ partial, int NW, int B)
{
    __shared__ float acc[BKT_RANGE];

    const int b = blockIdx.x / CCHUNK;
    const int c = blockIdx.x % CCHUNK;

    for (int i = threadIdx.x; i < BKT_RANGE; i += 256) acc[i] = 0.f;
    __syncthreads();

    const int wpc = (NW + CCHUNK - 1) / CCHUNK;
    const int w0 = c * wpc;
    const int w1 = (w0 + wpc < NW) ? w0 + wpc : NW;
    const int nb = b + 1;
    const int base_node = b << BKT_SHIFT;

    for (int w = w0 + threadIdx.x; w < w1; w += 256) {
        ull ov = offs[w];
        uint32_t lo = (uint32_t)ov, hi = (uint32_t)(ov >> 32);
        int ob = (int)(((b  < 4) ? (lo >> (8 * b))  : (hi >> (8 * (b  - 4)))) & 0xFF);
        int oe = (int)(((nb < 4) ? (lo >> (8 * nb)) : (hi >> (8 * (nb - 4)))) & 0xFF);
        const uint2* rb = recs + (size_t)w * 64;
        for (int r = ob; r < oe; ++r) {
            uint2 rec = rb[r];
            atomicAdd(&acc[(int)rec.x - base_node], __uint_as_float(rec.y));
        }
    }
    __syncthreads();

    float* pb = partial + ((size_t)b * CCHUNK + c) * BKT_RANGE;
    for (int i = threadIdx.x; i < BKT_RANGE; i += 256) pb[i] = acc[i];
}

__global__ __launch_bounds__(256) void bucket_reduce_kernel(
    const float* __restrict__ partial, float* __restrict__ agg, int N)
{
    int n = blockIdx.x * 256 + threadIdx.x;
    if (n >= N) return;
    int b = n >> BKT_SHIFT, nl = n & (BKT_RANGE - 1);
    const float* p = partial + (size_t)b * CCHUNK * BKT_RANGE + nl;
    float s = 0.f;
#pragma unroll 8
    for (int c = 0; c < CCHUNK; ++c) s += p[(size_t)c * BKT_RANGE];
    agg[n] = s;
}

// ---------------------------------------------------------------------------
// Node v3: 4-wave blocks, 64 nodes per wave (unchanged from round 8).
// ---------------------------------------------------------------------------
__global__ __launch_bounds__(256, 2) void node_mfma3_kernel(
    const float* __restrict__ nf, const float* __restrict__ agg,
    const int* __restrict__ gid,
    const unsigned short* __restrict__ nw1x, const unsigned short* __restrict__ nw2T,
    const float* __restrict__ nb2, const float* __restrict__ nw3, const float* __restrict__ nb3,
    const unsigned short* __restrict__ mw1x, const unsigned short* __restrict__ mw2T,
    const float* __restrict__ mb2, const float* __restrict__ mw3, const float* __restrict__ mb3,
    float* __restrict__ rd, int N)
{
    __shared__ uint2 tile[4][4][16][16];   // 32 KB

    const int tid  = threadIdx.x;
    const int lane = tid & 63;
    const int wid  = tid >> 6;
    const int g    = lane >> 4;
    const int eL   = lane & 15;

    const int idx = blockIdx.x * 256 + tid;
    const int i   = idx < N ? idx : N - 1;
    const float x0 = nf[i];
    const float x1 = agg[i];
    const int   gg = gid[i];

    float myunf = 0.f, o = 0.f;

    // ================= MLP-N: [nf, agg] -> unf =================
    {
        FragU af1[4], af2[4][2];
        f32x4 b2v4[4]; uint32_t w3p[8];
#pragma unroll
        for (int t = 0; t < 4; ++t) {
            uint4 q = *(const uint4*)&nw1x[(t * 16 + eL) * 8];
            af1[t].q = (g == 0) ? q : make_uint4(0, 0, 0, 0);
#pragma unroll
            for (int h = 0; h < 2; ++h)
                af2[t][h].q = *(const uint4*)&nw2T[(t * 16 + eL) * 64 + h * 32 + g * 8];
            int j = t * 16 + g * 4;
            b2v4[t] = *(const f32x4*)&nb2[j];
            f32x4 wv = *(const f32x4*)&nw3[j];
            w3p[2 * t]     = cvt_pk_bf16(wv[0], wv[1]);
            w3p[2 * t + 1] = cvt_pk_bf16(wv[2], wv[3]);
        }

#pragma unroll
        for (int s = 0; s < 4; ++s) {
            float av = __shfl(x0, s * 16 + eL);
            float bv = __shfl(x1, s * 16 + eL);
            FragU bin;
            bin.u[0] = (g == 0) ? cvt_pk_bf16(av, bv) : 0u;
            bin.u[1] = (g == 0) ? cvt_pk_bf16(1.0f, 0.f) : 0u;
            bin.u[2] = 0u; bin.u[3] = 0u;
#pragma unroll
            for (int t = 0; t < 4; ++t) {
                f32x4 h4 = __builtin_amdgcn_mfma_f32_16x16x32_bf16(
                    af1[t].v, bin.v, (f32x4){0.f, 0.f, 0.f, 0.f}, 0, 0, 0);
                uint32_t p0 = cvt_pk_bf16(fmaxf(h4[0], 0.f), fmaxf(h4[1], 0.f));
                uint32_t p1 = cvt_pk_bf16(fmaxf(h4[2], 0.f), fmaxf(h4[3], 0.f));
                tile[wid][s][eL][(4 * t + g) ^ ((eL & 7) << 1)] = make_uint2(p0, p1);
            }
        }
#pragma unroll
        for (int s = 0; s < 4; ++s) {
            const uint4* row = (const uint4*)&tile[wid][s][eL][0];
            FragU bf0, bf1;
            bf0.q = row[(g)     ^ (eL & 7)];
            bf1.q = row[(4 + g) ^ (eL & 7)];
            float p = 0.f;
#pragma unroll
            for (int t = 0; t < 4; ++t) {
                f32x4 ac = __builtin_amdgcn_mfma_f32_16x16x32_bf16(af2[t][0].v, bf0.v, b2v4[t], 0, 0, 0);
                ac = __builtin_amdgcn_mfma_f32_16x16x32_bf16(af2[t][1].v, bf1.v, ac, 0, 0, 0);
                p = fmaf(fmaxf(ac[0], 0.f), bf16lo_f(w3p[2 * t]),     p);
                p = fmaf(fmaxf(ac[1], 0.f), bf16hi_f(w3p[2 * t]),     p);
                p = fmaf(fmaxf(ac[2], 0.f), bf16lo_f(w3p[2 * t + 1]), p);
                p = fmaf(fmaxf(ac[3], 0.f), bf16hi_f(w3p[2 * t + 1]), p);
            }
            p += __shfl_xor(p, 16);
            p += __shfl_xor(p, 32);
            if (s == g) myunf = p + nb3[0];
        }
    }

    // ================= MLP-M: unf -> o =================
    {
        FragU af1[4], af2[4][2];
        f32x4 b2v4[4]; uint32_t w3p[8];
#pragma unroll
        for (int t = 0; t < 4; ++t) {
            uint4 q = *(const uint4*)&mw1x[(t * 16 + eL) * 8];
            af1[t].q = (g == 0) ? q : make_uint4(0, 0, 0, 0);
#pragma unroll
            for (int h = 0; h < 2; ++h)
                af2[t][h].q = *(const uint4*)&mw2T[(t * 16 + eL) * 64 + h * 32 + g * 8];
            int j = t * 16 + g * 4;
            b2v4[t] = *(const f32x4*)&mb2[j];
            f32x4 wv = *(const f32x4*)&mw3[j];
            w3p[2 * t]     = cvt_pk_bf16(wv[0], wv[1]);
            w3p[2 * t + 1] = cvt_pk_bf16(wv[2], wv[3]);
        }

#pragma unroll
        for (int s = 0; s < 4; ++s) {
            float uv = __shfl(myunf, s * 16 + eL);
            FragU bin;
            bin.u[0] = (g == 0) ? cvt_pk_bf16(uv, 1.0f) : 0u;
            bin.u[1] = 0u; bin.u[2] = 0u; bin.u[3] = 0u;
#pragma unroll
            for (int t = 0; t < 4; ++t) {
                f32x4 h4 = __builtin_amdgcn_mfma_f32_16x16x32_bf16(
                    af1[t].v, bin.v, (f32x4){0.f, 0.f, 0.f, 0.f}, 0, 0, 0);
                uint32_t p0 = cvt_pk_bf16(fmaxf(h4[0], 0.f), fmaxf(h4[1], 0.f));
                uint32_t p1 = cvt_pk_bf16(fmaxf(h4[2], 0.f), fmaxf(h4[3], 0.f));
                tile[wid][s][eL][(4 * t + g) ^ ((eL & 7) << 1)] = make_uint2(p0, p1);
            }
        }
#pragma unroll
        for (int s = 0; s < 4; ++s) {
            const uint4* row = (const uint4*)&tile[wid][s][eL][0];
            FragU bf0, bf1;
            bf0.q = row[(g)     ^ (eL & 7)];
            bf1.q = row[(4 + g) ^ (eL & 7)];
            float p = 0.f;
#pragma unroll
            for (int t = 0; t < 4; ++t) {
                f32x4 ac = __builtin_amdgcn_mfma_f32_16x16x32_bf16(af2[t][0].v, bf0.v, b2v4[t], 0, 0, 0);
                ac = __builtin_amdgcn_mfma_f32_16x16x32_bf16(af2[t][1].v, bf1.v, ac, 0, 0, 0);
                p = fmaf(fmaxf(ac[0], 0.f), bf16lo_f(w3p[2 * t]),     p);
                p = fmaf(fmaxf(ac[1], 0.f), bf16hi_f(w3p[2 * t]),     p);
                p = fmaf(fmaxf(ac[2], 0.f), bf16lo_f(w3p[2 * t + 1]), p);
                p = fmaf(fmaxf(ac[3], 0.f), bf16hi_f(w3p[2 * t + 1]), p);
            }
            p += __shfl_xor(p, 16);
            p += __shfl_xor(p, 32);
            if (s == g) o = p + mb3[0];
        }
    }

    const float node_out = 1.0f / (1.0f + expf(-o));

    // ---- segmented reduction over sorted gid, one atomic per run tail ----
    {
        const bool ok = idx < N;
        float v = ok ? node_out : 0.0f;
        int ggv = gg;
#pragma unroll
        for (int d = 1; d < 64; d <<= 1) {
            float vup = __shfl_up(v, d);
            int   gup = __shfl_up(ggv, d);
            if (lane >= d && gup == ggv) v += vup;
        }
        int gdn = __shfl_down(ggv, 1);
        bool tail = (lane == 63) || (gdn != ggv);
        if (tail)
            atomicAdd(&rd[ggv], v);
    }
}

__global__ void readout_kernel(const float* __restrict__ rd,
                               float* __restrict__ out, int G)
{
    int g = blockIdx.x * blockDim.x + threadIdx.x;
    if (g < G) out[g] = 1.0f / (1.0f + expf(-rd[g]));
}

extern "C" void kernel_launch(void* const* d_in, const int* in_sizes, int n_in,
                              void* d_out, int out_size, void* d_ws, size_t ws_size,
                              hipStream_t stream)
{
    const float* nf  = (const float*)d_in[0];
    const float* ef  = (const float*)d_in[1];
    const int*   src = (const int*)  d_in[2];
    const int*   dst = (const int*)  d_in[3];
    const int*   gid = (const int*)  d_in[4];

    const float* e_w1 = (const float*)d_in[5];
    const float* e_b1 = (const float*)d_in[6];
    const float* e_w2 = (const float*)d_in[7];
    const float* e_b2 = (const float*)d_in[8];
    const float* e_w3 = (const float*)d_in[9];
    const float* e_b3 = (const float*)d_in[10];

    const float* n_w1 = (const float*)d_in[11];
    const float* n_b1 = (const float*)d_in[12];
    const float* n_w2 = (const float*)d_in[13];
    const float* n_b2 = (const float*)d_in[14];
    const float* n_w3 = (const float*)d_in[15];
    const float* n_b3 = (const float*)d_in[16];

    const float* m_w1 = (const float*)d_in[17];
    const float* m_b1 = (const float*)d_in[18];
    const float* m_w2 = (const float*)d_in[19];
    const float* m_b2 = (const float*)d_in[20];
    const float* m_w3 = (const float*)d_in[21];
    const float* m_b3 = (const float*)d_in[22];

    const int N = in_sizes[0];   // 50000
    const int E = in_sizes[2];   // 1600000
    const int G = out_size;      // 512

    const int nbatch = (E + 255) / 256;
    const int NW = (E + 63) / 64;
    const int B  = (N + BKT_RANGE - 1) / BKT_RANGE;

    size_t wts_b  = 32 * 1024;
    size_t recs_b = (size_t)NW * 64 * sizeof(uint2);
    size_t offs_b = (size_t)NW * sizeof(ull);
    size_t part_b = (size_t)B * CCHUNK * BKT_RANGE * sizeof(float);
    size_t need   = wts_b + recs_b + offs_b + part_b + ((size_t)N + G) * sizeof(float);
    bool bucketok = (B <= 8) && (need <= ws_size);

    char* wp = (char*)d_ws;
    unsigned short* w1x  = (unsigned short*)(wp);
    unsigned short* nw1x = (unsigned short*)(wp + 1024);
    unsigned short* mw1x = (unsigned short*)(wp + 2048);
    unsigned short* w2T  = (unsigned short*)(wp + 4096);
    unsigned short* nw2T = (unsigned short*)(wp + 4096 + 8192);
    unsigned short* mw2T = (unsigned short*)(wp + 4096 + 16384);

    float* out = (float*)d_out;

    prep_kernel<<<16, 256, 0, stream>>>(
        e_w1, e_b1, e_w2, n_w1, n_b1, n_w2, m_w1, m_b1, m_w2,
        w1x, w2T, nw1x, nw2T, mw1x, mw2T);

    int egrid = nbatch < 1536 ? nbatch : 1536;

    if (bucketok) {
        uint2* recs    = (uint2*)(wp + wts_b);
        ull*   offs    = (ull*)(wp + wts_b + recs_b);
        float* partial = (float*)(wp + wts_b + recs_b + offs_b);
        float* agg     = (float*)(wp + wts_b + recs_b + offs_b + part_b);
        float* rd      = agg + N;

        hipMemsetAsync(rd, 0, (size_t)G * sizeof(float), stream);

        edge_mfma4_kernel<<<egrid, 256, 0, stream>>>(
            nf, ef, src, dst, w1x, w2T, e_b2, e_w3, e_b3,
            recs, offs, nullptr, E, B, nbatch, 0);

        bucket_accum_kernel<<<B * CCHUNK, 256, 0, stream>>>(
            recs, offs, partial, NW, B);

        bucket_reduce_kernel<<<(N + 255) / 256, 256, 0, stream>>>(
            partial, agg, N);

        node_mfma3_kernel<<<(N + 255) / 256, 256, 0, stream>>>(
            nf, agg, gid,
            nw1x, nw2T, n_b2, n_w3, n_b3,
            mw1x, mw2T, m_b2, m_w3, m_b3,
            rd, N);

        readout_kernel<<<(G + 255) / 256, 256, 0, stream>>>(rd, out, G);
    } else {
        float* agg = (float*)(wp + wts_b);
        float* rd  = agg + N;

        hipMemsetAsync(agg, 0, ((size_t)N + G) * sizeof(float), stream);

        edge_mfma4_kernel<<<egrid, 256, 0, stream>>>(
            nf, ef, src, dst, w1x, w2T, e_b2, e_w3, e_b3,
            nullptr, nullptr, agg, E, B, nbatch, 1);

        node_mfma3_kernel<<<(N + 255) / 256, 256, 0, stream>>>(
            nf, agg, gid,
            nw1x, nw2T, n_b2, n_w3, n_b3,
            mw1x, mw2T, m_b2, m_w3, m_b3,
            rd, N);

        readout_kernel<<<(G + 255) / 256, 256, 0, stream>>>(rd, out, G);
    }
}

// Round 10
// 80.239 us; speedup vs baseline: 3.2765x; 3.2765x over previous
//
#include <hip/hip_runtime.h>
#include <math.h>

#define HID 64
#define BKT_SHIFT 13                 // 8192 nodes per bucket
#define BKT_RANGE 8192
#define CCHUNK 32                    // wave-chunks per bucket in phase B

typedef __attribute__((ext_vector_type(8))) short short8;
typedef __attribute__((ext_vector_type(4))) float f32x4;
typedef unsigned long long ull;

union FragU {
    uint4 q;
    short8 v;
    uint32_t u[4];
};

__device__ __forceinline__ uint32_t cvt_pk_bf16(float lo, float hi) {
    uint32_t r;
    asm("v_cvt_pk_bf16_f32 %0, %1, %2" : "=v"(r) : "v"(lo), "v"(hi));
    return r;
}
__device__ __forceinline__ float bf16lo_f(uint32_t u) { return __uint_as_float(u << 16); }
__device__ __forceinline__ float bf16hi_f(uint32_t u) { return __uint_as_float(u & 0xFFFF0000u); }
__device__ __forceinline__ unsigned short bf16_of(float v) {
    return (unsigned short)(cvt_pk_bf16(v, 0.f) & 0xFFFFu);
}

// ---------------------------------------------------------------------------
// Prep: bf16-transposed weights (identical to rounds 7-9).
// ---------------------------------------------------------------------------
__global__ void prep_kernel(
    const float* __restrict__ w1,  const float* __restrict__ b1,  const float* __restrict__ w2,
    const float* __restrict__ nw1, const float* __restrict__ nb1, const float* __restrict__ nw2,
    const float* __restrict__ mw1, const float* __restrict__ mb1, const float* __restrict__ mw2,
    unsigned short* __restrict__ w1x,  unsigned short* __restrict__ w2T,
    unsigned short* __restrict__ nw1x, unsigned short* __restrict__ nw2T,
    unsigned short* __restrict__ mw1x, unsigned short* __restrict__ mw2T)
{
    int t = blockIdx.x * 256 + threadIdx.x;
    if (t < 4096) {
        int j = t >> 6, k = t & 63;
        w2T [t] = bf16_of(w2 [k * HID + j]);
        nw2T[t] = bf16_of(nw2[k * HID + j]);
        mw2T[t] = bf16_of(mw2[k * HID + j]);
    }
    if (t < 512) {
        int j = t >> 3, k = t & 7;
        float ve = k == 0 ? w1[j] : k == 1 ? w1[HID + j] : k == 2 ? w1[2 * HID + j] : k == 3 ? b1[j] : 0.f;
        float vn = k == 0 ? nw1[j] : k == 1 ? nw1[HID + j] : k == 2 ? nb1[j] : 0.f;
        float vm = k == 0 ? mw1[j] : k == 1 ? mb1[j] : 0.f;
        w1x [t] = bf16_of(ve);
        nw1x[t] = bf16_of(vn);
        mw1x[t] = bf16_of(vm);
    }
}

// ---------------------------------------------------------------------------
// Edge v6: persistent + pipelined + 2-phase (16 KB LDS). launch_bounds floor
// (256,2) so the allocator keeps the ~90-VGPR weight set RESIDENT (round 9's
// (256,6) clamped to 40 VGPR -> 632 MB of scratch spills). Occupancy comes
// from grid = 2048 (8 blocks/CU; LDS allows 10, VGPR~64-100 allows ~8).
// ---------------------------------------------------------------------------
__global__ __launch_bounds__(256, 2) void edge_mfma5_kernel(
    const float* __restrict__ nf, const float* __restrict__ ef,
    const int* __restrict__ src, const int* __restrict__ dst,
    const unsigned short* __restrict__ w1x, const unsigned short* __restrict__ w2T,
    const float* __restrict__ b2, const float* __restrict__ w3, const float* __restrict__ b3,
    uint2* __restrict__ recs, ull* __restrict__ offs,
    float* __restrict__ aggFb, int E, int B, int nbatch, int mode)
{
    __shared__ uint2 tile[4][2][16][16];   // [wave][set-in-phase][row][chunk] = 16 KB

    const int tid  = threadIdx.x;
    const int lane = tid & 63;
    const int wid  = tid >> 6;
    const int g    = lane >> 4;
    const int eL   = lane & 15;

    // ---- weights: once per block, kept in VGPRs ----
    FragU af1[4];
#pragma unroll
    for (int t = 0; t < 4; ++t) {
        uint4 q = *(const uint4*)&w1x[(t * 16 + eL) * 8];
        af1[t].q = (g == 0) ? q : make_uint4(0, 0, 0, 0);
    }
    FragU af2[4][2];
#pragma unroll
    for (int t = 0; t < 4; ++t)
#pragma unroll
        for (int h = 0; h < 2; ++h)
            af2[t][h].q = *(const uint4*)&w2T[(t * 16 + eL) * 64 + h * 32 + g * 8];

    f32x4 b2v4[4];
    uint32_t w3p[8];
#pragma unroll
    for (int t = 0; t < 4; ++t) {
        int j = t * 16 + g * 4;
        b2v4[t] = *(const f32x4*)&b2[j];
        f32x4 wv = *(const f32x4*)&w3[j];
        w3p[2 * t]     = cvt_pk_bf16(wv[0], wv[1]);
        w3p[2 * t + 1] = cvt_pk_bf16(wv[2], wv[3]);
    }
    const float b3c = b3[0];

    // ---- first batch loads ----
    int bi   = blockIdx.x;
    if (bi >= nbatch) return;
    int eidx = bi * 256 + tid;
    int ei   = eidx < E ? eidx : E - 1;
    int dcur = dst[ei];
    float a  = nf[src[ei]];
    float b  = nf[dcur];
    float c  = ef[ei];

    for (;;) {
        // ---- prefetch next batch indices (issued early, consumed late) ----
        const int nbi   = bi + gridDim.x;
        const bool hn   = nbi < nbatch;
        const int neidx = hn ? nbi * 256 + tid : eidx;
        const int nei   = neidx < E ? neidx : E - 1;
        const int ns    = src[nei];
        const int nd    = dst[nei];
        const float ncf = ef[nei];

        float na = 0.f, nb = 0.f;
        float mymsg = 0.f;

#pragma unroll
        for (int ph = 0; ph < 2; ++ph) {
            // ---- L1 phase for sets 2ph, 2ph+1 ----
#pragma unroll
            for (int ss = 0; ss < 2; ++ss) {
                const int s = 2 * ph + ss;
                float av = __shfl(a, s * 16 + eL);
                float bv = __shfl(b, s * 16 + eL);
                float cv = __shfl(c, s * 16 + eL);
                FragU bin;
                bin.u[0] = (g == 0) ? cvt_pk_bf16(av, bv) : 0u;
                bin.u[1] = (g == 0) ? cvt_pk_bf16(cv, 1.0f) : 0u;
                bin.u[2] = 0u; bin.u[3] = 0u;
#pragma unroll
                for (int t = 0; t < 4; ++t) {
                    f32x4 h4 = __builtin_amdgcn_mfma_f32_16x16x32_bf16(
                        af1[t].v, bin.v, (f32x4){0.f, 0.f, 0.f, 0.f}, 0, 0, 0);
                    uint32_t p0 = cvt_pk_bf16(fmaxf(h4[0], 0.f), fmaxf(h4[1], 0.f));
                    uint32_t p1 = cvt_pk_bf16(fmaxf(h4[2], 0.f), fmaxf(h4[3], 0.f));
                    tile[wid][ss][eL][(4 * t + g) ^ ((eL & 7) << 1)] = make_uint2(p0, p1);
                }
            }

            // ---- gathers for next batch: issue once, hidden under L2+phase1 ----
            if (ph == 0) {
                na = nf[ns];
                nb = nf[nd];
            }

            // ---- L2 phase for sets 2ph, 2ph+1 ----
#pragma unroll
            for (int ss = 0; ss < 2; ++ss) {
                const int s = 2 * ph + ss;
                const uint4* row = (const uint4*)&tile[wid][ss][eL][0];
                FragU bf0, bf1;
                bf0.q = row[(g)     ^ (eL & 7)];
                bf1.q = row[(4 + g) ^ (eL & 7)];

                float q0, q1, q2, q3;
                {
                    f32x4 ac = __builtin_amdgcn_mfma_f32_16x16x32_bf16(af2[0][0].v, bf0.v, b2v4[0], 0, 0, 0);
                    ac = __builtin_amdgcn_mfma_f32_16x16x32_bf16(af2[0][1].v, bf1.v, ac, 0, 0, 0);
                    q0 = fmaxf(ac[0], 0.f) * bf16lo_f(w3p[0]);
                    q0 = fmaf(fmaxf(ac[1], 0.f), bf16hi_f(w3p[0]), q0);
                    q0 = fmaf(fmaxf(ac[2], 0.f), bf16lo_f(w3p[1]), q0);
                    q0 = fmaf(fmaxf(ac[3], 0.f), bf16hi_f(w3p[1]), q0);
                }
                {
                    f32x4 ac = __builtin_amdgcn_mfma_f32_16x16x32_bf16(af2[1][0].v, bf0.v, b2v4[1], 0, 0, 0);
                    ac = __builtin_amdgcn_mfma_f32_16x16x32_bf16(af2[1][1].v, bf1.v, ac, 0, 0, 0);
                    q1 = fmaxf(ac[0], 0.f) * bf16lo_f(w3p[2]);
                    q1 = fmaf(fmaxf(ac[1], 0.f), bf16hi_f(w3p[2]), q1);
                    q1 = fmaf(fmaxf(ac[2], 0.f), bf16lo_f(w3p[3]), q1);
                    q1 = fmaf(fmaxf(ac[3], 0.f), bf16hi_f(w3p[3]), q1);
                }
                {
                    f32x4 ac = __builtin_amdgcn_mfma_f32_16x16x32_bf16(af2[2][0].v, bf0.v, b2v4[2], 0, 0, 0);
                    ac = __builtin_amdgcn_mfma_f32_16x16x32_bf16(af2[2][1].v, bf1.v, ac, 0, 0, 0);
                    q2 = fmaxf(ac[0], 0.f) * bf16lo_f(w3p[4]);
                    q2 = fmaf(fmaxf(ac[1], 0.f), bf16hi_f(w3p[4]), q2);
                    q2 = fmaf(fmaxf(ac[2], 0.f), bf16lo_f(w3p[5]), q2);
                    q2 = fmaf(fmaxf(ac[3], 0.f), bf16hi_f(w3p[5]), q2);
                }
                {
                    f32x4 ac = __builtin_amdgcn_mfma_f32_16x16x32_bf16(af2[3][0].v, bf0.v, b2v4[3], 0, 0, 0);
                    ac = __builtin_amdgcn_mfma_f32_16x16x32_bf16(af2[3][1].v, bf1.v, ac, 0, 0, 0);
                    q3 = fmaxf(ac[0], 0.f) * bf16lo_f(w3p[6]);
                    q3 = fmaf(fmaxf(ac[1], 0.f), bf16hi_f(w3p[6]), q3);
                    q3 = fmaf(fmaxf(ac[2], 0.f), bf16lo_f(w3p[7]), q3);
                    q3 = fmaf(fmaxf(ac[3], 0.f), bf16hi_f(w3p[7]), q3);
                }
                float p = (q0 + q1) + (q2 + q3);
                p += __shfl_xor(p, 16);
                p += __shfl_xor(p, 32);
                if (s == g) mymsg = p + b3c;
            }
        }

        const bool valid = eidx < E;

        if (mode == 1) {
            if (valid) atomicAdd(&aggFb[dcur], mymsg);
        } else {
            // ---- bucket append: coalesced wave-private, zero atomics ----
            const int bkt = dcur >> BKT_SHIFT;
            const ull lt = (1ull << lane) - 1;
            int myslot = 0;
            int off = 0;
            uint32_t pack_lo = 0, pack_hi = 0;
            for (int bb = 0; bb < B; ++bb) {
                if (bb < 4) pack_lo |= (uint32_t)off << (8 * bb);
                else        pack_hi |= (uint32_t)off << (8 * (bb - 4));
                ull m = __ballot(valid && bkt == bb);
                if (valid && bkt == bb) myslot = off + (int)__popcll(m & lt);
                off += (int)__popcll(m);
            }
            pack_hi |= (uint32_t)off << 24;

            const size_t wgl = (size_t)bi * 4 + wid;
            if (valid) recs[wgl * 64 + myslot] = make_uint2((uint32_t)dcur, __float_as_uint(mymsg));
            if (lane == 0) offs[wgl] = ((ull)pack_hi << 32) | (ull)pack_lo;
        }

        if (!hn) break;
        bi = nbi; eidx = neidx; ei = nei;
        a = na; b = nb; c = ncf; dcur = nd;
    }
}

// ---------------------------------------------------------------------------
// Phase B: block (b,c) accumulates bucket b's records from wave-chunk c into
// a 32KB LDS array (LDS atomics), then writes a dense partial plane.
// ---------------------------------------------------------------------------
__global__ __launch_bounds__(256) void bucket_accum_kernel(
    const uint2* __restrict__ recs, const ull* __restrict__ offs,
    float* __restrict__ partial, int NW, int B)
{
    __shared__ float acc[BKT_RANGE];

    const int b = blockIdx.x / CCHUNK;
    const int c = blockIdx.x % CCHUNK;

    for (int i = threadIdx.x; i < BKT_RANGE; i += 256) acc[i] = 0.f;
    __syncthreads();

    const int wpc = (NW + CCHUNK - 1) / CCHUNK;
    const int w0 = c * wpc;
    const int w1 = (w0 + wpc < NW) ? w0 + wpc : NW;
    const int nb = b + 1;
    const int base_node = b << BKT_SHIFT;

    for (int w = w0 + threadIdx.x; w < w1; w += 256) {
        ull ov = offs[w];
        uint32_t lo = (uint32_t)ov, hi = (uint32_t)(ov >> 32);
        int ob = (int)(((b  < 4) ? (lo >> (8 * b))  : (hi >> (8 * (b  - 4)))) & 0xFF);
        int oe = (int)(((nb < 4) ? (lo >> (8 * nb)) : (hi >> (8 * (nb - 4)))) & 0xFF);
        const uint2* rb = recs + (size_t)w * 64;
        for (int r = ob; r < oe; ++r) {
            uint2 rec = rb[r];
            atomicAdd(&acc[(int)rec.x - base_node], __uint_as_float(rec.y));
        }
    }
    __syncthreads();

    float* pb = partial + ((size_t)b * CCHUNK + c) * BKT_RANGE;
    for (int i = threadIdx.x; i < BKT_RANGE; i += 256) pb[i] = acc[i];
}

__global__ __launch_bounds__(256) void bucket_reduce_kernel(
    const float* __restrict__ partial, float* __restrict__ agg, int N)
{
    int n = blockIdx.x * 256 + threadIdx.x;
    if (n >= N) return;
    int b = n >> BKT_SHIFT, nl = n & (BKT_RANGE - 1);
    const float* p = partial + (size_t)b * CCHUNK * BKT_RANGE + nl;
    float s = 0.f;
#pragma unroll 8
    for (int c = 0; c < CCHUNK; ++c) s += p[(size_t)c * BKT_RANGE];
    agg[n] = s;
}

// ---------------------------------------------------------------------------
// Node v3: 4-wave blocks, 64 nodes per wave (unchanged from round 8).
// ---------------------------------------------------------------------------
__global__ __launch_bounds__(256, 2) void node_mfma3_kernel(
    const float* __restrict__ nf, const float* __restrict__ agg,
    const int* __restrict__ gid,
    const unsigned short* __restrict__ nw1x, const unsigned short* __restrict__ nw2T,
    const float* __restrict__ nb2, const float* __restrict__ nw3, const float* __restrict__ nb3,
    const unsigned short* __restrict__ mw1x, const unsigned short* __restrict__ mw2T,
    const float* __restrict__ mb2, const float* __restrict__ mw3, const float* __restrict__ mb3,
    float* __restrict__ rd, int N)
{
    __shared__ uint2 tile[4][4][16][16];   // 32 KB

    const int tid  = threadIdx.x;
    const int lane = tid & 63;
    const int wid  = tid >> 6;
    const int g    = lane >> 4;
    const int eL   = lane & 15;

    const int idx = blockIdx.x * 256 + tid;
    const int i   = idx < N ? idx : N - 1;
    const float x0 = nf[i];
    const float x1 = agg[i];
    const int   gg = gid[i];

    float myunf = 0.f, o = 0.f;

    // ================= MLP-N: [nf, agg] -> unf =================
    {
        FragU af1[4], af2[4][2];
        f32x4 b2v4[4]; uint32_t w3p[8];
#pragma unroll
        for (int t = 0; t < 4; ++t) {
            uint4 q = *(const uint4*)&nw1x[(t * 16 + eL) * 8];
            af1[t].q = (g == 0) ? q : make_uint4(0, 0, 0, 0);
#pragma unroll
            for (int h = 0; h < 2; ++h)
                af2[t][h].q = *(const uint4*)&nw2T[(t * 16 + eL) * 64 + h * 32 + g * 8];
            int j = t * 16 + g * 4;
            b2v4[t] = *(const f32x4*)&nb2[j];
            f32x4 wv = *(const f32x4*)&nw3[j];
            w3p[2 * t]     = cvt_pk_bf16(wv[0], wv[1]);
            w3p[2 * t + 1] = cvt_pk_bf16(wv[2], wv[3]);
        }

#pragma unroll
        for (int s = 0; s < 4; ++s) {
            float av = __shfl(x0, s * 16 + eL);
            float bv = __shfl(x1, s * 16 + eL);
            FragU bin;
            bin.u[0] = (g == 0) ? cvt_pk_bf16(av, bv) : 0u;
            bin.u[1] = (g == 0) ? cvt_pk_bf16(1.0f, 0.f) : 0u;
            bin.u[2] = 0u; bin.u[3] = 0u;
#pragma unroll
            for (int t = 0; t < 4; ++t) {
                f32x4 h4 = __builtin_amdgcn_mfma_f32_16x16x32_bf16(
                    af1[t].v, bin.v, (f32x4){0.f, 0.f, 0.f, 0.f}, 0, 0, 0);
                uint32_t p0 = cvt_pk_bf16(fmaxf(h4[0], 0.f), fmaxf(h4[1], 0.f));
                uint32_t p1 = cvt_pk_bf16(fmaxf(h4[2], 0.f), fmaxf(h4[3], 0.f));
                tile[wid][s][eL][(4 * t + g) ^ ((eL & 7) << 1)] = make_uint2(p0, p1);
            }
        }
#pragma unroll
        for (int s = 0; s < 4; ++s) {
            const uint4* row = (const uint4*)&tile[wid][s][eL][0];
            FragU bf0, bf1;
            bf0.q = row[(g)     ^ (eL & 7)];
            bf1.q = row[(4 + g) ^ (eL & 7)];
            float p = 0.f;
#pragma unroll
            for (int t = 0; t < 4; ++t) {
                f32x4 ac = __builtin_amdgcn_mfma_f32_16x16x32_bf16(af2[t][0].v, bf0.v, b2v4[t], 0, 0, 0);
                ac = __builtin_amdgcn_mfma_f32_16x16x32_bf16(af2[t][1].v, bf1.v, ac, 0, 0, 0);
                p = fmaf(fmaxf(ac[0], 0.f), bf16lo_f(w3p[2 * t]),     p);
                p = fmaf(fmaxf(ac[1], 0.f), bf16hi_f(w3p[2 * t]),     p);
                p = fmaf(fmaxf(ac[2], 0.f), bf16lo_f(w3p[2 * t + 1]), p);
                p = fmaf(fmaxf(ac[3], 0.f), bf16hi_f(w3p[2 * t + 1]), p);
            }
            p += __shfl_xor(p, 16);
            p += __shfl_xor(p, 32);
            if (s == g) myunf = p + nb3[0];
        }
    }

    // ================= MLP-M: unf -> o =================
    {
        FragU af1[4], af2[4][2];
        f32x4 b2v4[4]; uint32_t w3p[8];
#pragma unroll
        for (int t = 0; t < 4; ++t) {
            uint4 q = *(const uint4*)&mw1x[(t * 16 + eL) * 8];
            af1[t].q = (g == 0) ? q : make_uint4(0, 0, 0, 0);
#pragma unroll
            for (int h = 0; h < 2; ++h)
                af2[t][h].q = *(const uint4*)&mw2T[(t * 16 + eL) * 64 + h * 32 + g * 8];
            int j = t * 16 + g * 4;
            b2v4[t] = *(const f32x4*)&mb2[j];
            f32x4 wv = *(const f32x4*)&mw3[j];
            w3p[2 * t]     = cvt_pk_bf16(wv[0], wv[1]);
            w3p[2 * t + 1] = cvt_pk_bf16(wv[2], wv[3]);
        }

#pragma unroll
        for (int s = 0; s < 4; ++s) {
            float uv = __shfl(myunf, s * 16 + eL);
            FragU bin;
            bin.u[0] = (g == 0) ? cvt_pk_bf16(uv, 1.0f) : 0u;
            bin.u[1] = 0u; bin.u[2] = 0u; bin.u[3] = 0u;
#pragma unroll
            for (int t = 0; t < 4; ++t) {
                f32x4 h4 = __builtin_amdgcn_mfma_f32_16x16x32_bf16(
                    af1[t].v, bin.v, (f32x4){0.f, 0.f, 0.f, 0.f}, 0, 0, 0);
                uint32_t p0 = cvt_pk_bf16(fmaxf(h4[0], 0.f), fmaxf(h4[1], 0.f));
                uint32_t p1 = cvt_pk_bf16(fmaxf(h4[2], 0.f), fmaxf(h4[3], 0.f));
                tile[wid][s][eL][(4 * t + g) ^ ((eL & 7) << 1)] = make_uint2(p0, p1);
            }
        }
#pragma unroll
        for (int s = 0; s < 4; ++s) {
            const uint4* row = (const uint4*)&tile[wid][s][eL][0];
            FragU bf0, bf1;
            bf0.q = row[(g)     ^ (eL & 7)];
            bf1.q = row[(4 + g) ^ (eL & 7)];
            float p = 0.f;
#pragma unroll
            for (int t = 0; t < 4; ++t) {
                f32x4 ac = __builtin_amdgcn_mfma_f32_16x16x32_bf16(af2[t][0].v, bf0.v, b2v4[t], 0, 0, 0);
                ac = __builtin_amdgcn_mfma_f32_16x16x32_bf16(af2[t][1].v, bf1.v, ac, 0, 0, 0);
                p = fmaf(fmaxf(ac[0], 0.f), bf16lo_f(w3p[2 * t]),     p);
                p = fmaf(fmaxf(ac[1], 0.f), bf16hi_f(w3p[2 * t]),     p);
                p = fmaf(fmaxf(ac[2], 0.f), bf16lo_f(w3p[2 * t + 1]), p);
                p = fmaf(fmaxf(ac[3], 0.f), bf16hi_f(w3p[2 * t + 1]), p);
            }
            p += __shfl_xor(p, 16);
            p += __shfl_xor(p, 32);
            if (s == g) o = p + mb3[0];
        }
    }

    const float node_out = 1.0f / (1.0f + expf(-o));

    // ---- segmented reduction over sorted gid, one atomic per run tail ----
    {
        const bool ok = idx < N;
        float v = ok ? node_out : 0.0f;
        int ggv = gg;
#pragma unroll
        for (int d = 1; d < 64; d <<= 1) {
            float vup = __shfl_up(v, d);
            int   gup = __shfl_up(ggv, d);
            if (lane >= d && gup == ggv) v += vup;
        }
        int gdn = __shfl_down(ggv, 1);
        bool tail = (lane == 63) || (gdn != ggv);
        if (tail)
            atomicAdd(&rd[ggv], v);
    }
}

__global__ void readout_kernel(const float* __restrict__ rd,
                               float* __restrict__ out, int G)
{
    int g = blockIdx.x * blockDim.x + threadIdx.x;
    if (g < G) out[g] = 1.0f / (1.0f + expf(-rd[g]));
}

extern "C" void kernel_launch(void* const* d_in, const int* in_sizes, int n_in,
                              void* d_out, int out_size, void* d_ws, size_t ws_size,
                              hipStream_t stream)
{
    const float* nf  = (const float*)d_in[0];
    const float* ef  = (const float*)d_in[1];
    const int*   src = (const int*)  d_in[2];
    const int*   dst = (const int*)  d_in[3];
    const int*   gid = (const int*)  d_in[4];

    const float* e_w1 = (const float*)d_in[5];
    const float* e_b1 = (const float*)d_in[6];
    const float* e_w2 = (const float*)d_in[7];
    const float* e_b2 = (const float*)d_in[8];
    const float* e_w3 = (const float*)d_in[9];
    const float* e_b3 = (const float*)d_in[10];

    const float* n_w1 = (const float*)d_in[11];
    const float* n_b1 = (const float*)d_in[12];
    const float* n_w2 = (const float*)d_in[13];
    const float* n_b2 = (const float*)d_in[14];
    const float* n_w3 = (const float*)d_in[15];
    const float* n_b3 = (const float*)d_in[16];

    const float* m_w1 = (const float*)d_in[17];
    const float* m_b1 = (const float*)d_in[18];
    const float* m_w2 = (const float*)d_in[19];
    const float* m_b2 = (const float*)d_in[20];
    const float* m_w3 = (const float*)d_in[21];
    const float* m_b3 = (const float*)d_in[22];

    const int N = in_sizes[0];   // 50000
    const int E = in_sizes[2];   // 1600000
    const int G = out_size;      // 512

    const int nbatch = (E + 255) / 256;
    const int NW = (E + 63) / 64;
    const int B  = (N + BKT_RANGE - 1) / BKT_RANGE;

    size_t wts_b  = 32 * 1024;
    size_t recs_b = (size_t)NW * 64 * sizeof(uint2);
    size_t offs_b = (size_t)NW * sizeof(ull);
    size_t part_b = (size_t)B * CCHUNK * BKT_RANGE * sizeof(float);
    size_t need   = wts_b + recs_b + offs_b + part_b + ((size_t)N + G) * sizeof(float);
    bool bucketok = (B <= 8) && (need <= ws_size);

    char* wp = (char*)d_ws;
    unsigned short* w1x  = (unsigned short*)(wp);
    unsigned short* nw1x = (unsigned short*)(wp + 1024);
    unsigned short* mw1x = (unsigned short*)(wp + 2048);
    unsigned short* w2T  = (unsigned short*)(wp + 4096);
    unsigned short* nw2T = (unsigned short*)(wp + 4096 + 8192);
    unsigned short* mw2T = (unsigned short*)(wp + 4096 + 16384);

    float* out = (float*)d_out;

    prep_kernel<<<16, 256, 0, stream>>>(
        e_w1, e_b1, e_w2, n_w1, n_b1, n_w2, m_w1, m_b1, m_w2,
        w1x, w2T, nw1x, nw2T, mw1x, mw2T);

    int egrid = nbatch < 2048 ? nbatch : 2048;

    if (bucketok) {
        uint2* recs    = (uint2*)(wp + wts_b);
        ull*   offs    = (ull*)(wp + wts_b + recs_b);
        float* partial = (float*)(wp + wts_b + recs_b + offs_b);
        float* agg     = (float*)(wp + wts_b + recs_b + offs_b + part_b);
        float* rd      = agg + N;

        hipMemsetAsync(rd, 0, (size_t)G * sizeof(float), stream);

        edge_mfma5_kernel<<<egrid, 256, 0, stream>>>(
            nf, ef, src, dst, w1x, w2T, e_b2, e_w3, e_b3,
            recs, offs, nullptr, E, B, nbatch, 0);

        bucket_accum_kernel<<<B * CCHUNK, 256, 0, stream>>>(
            recs, offs, partial, NW, B);

        bucket_reduce_kernel<<<(N + 255) / 256, 256, 0, stream>>>(
            partial, agg, N);

        node_mfma3_kernel<<<(N + 255) / 256, 256, 0, stream>>>(
            nf, agg, gid,
            nw1x, nw2T, n_b2, n_w3, n_b3,
            mw1x, mw2T, m_b2, m_w3, m_b3,
            rd, N);

        readout_kernel<<<(G + 255) / 256, 256, 0, stream>>>(rd, out, G);
    } else {
        float* agg = (float*)(wp + wts_b);
        float* rd  = agg + N;

        hipMemsetAsync(agg, 0, ((size_t)N + G) * sizeof(float), stream);

        edge_mfma5_kernel<<<egrid, 256, 0, stream>>>(
            nf, ef, src, dst, w1x, w2T, e_b2, e_w3, e_b3,
            nullptr, nullptr, agg, E, B, nbatch, 1);

        node_mfma3_kernel<<<(N + 255) / 256, 256, 0, stream>>>(
            nf, agg, gid,
            nw1x, nw2T, n_b2, n_w3, n_b3,
            mw1x, mw2T, m_b2, m_w3, m_b3,
            rd, N);

        readout_kernel<<<(G + 255) / 256, 256, 0, stream>>>(rd, out, G);
    }
}

// Round 11
// 79.821 us; speedup vs baseline: 3.2937x; 1.0052x over previous
//
#include <hip/hip_runtime.h>
#include <math.h>

#define HID 64
#define BKT_SHIFT 13                 // 8192 nodes per bucket
#define BKT_RANGE 8192
#define CCHUNK 32                    // wave-chunks per bucket in phase B

typedef __attribute__((ext_vector_type(8))) short short8;
typedef __attribute__((ext_vector_type(4))) float f32x4;
typedef unsigned long long ull;

union FragU {
    uint4 q;
    short8 v;
    uint32_t u[4];
};

__device__ __forceinline__ uint32_t cvt_pk_bf16(float lo, float hi) {
    uint32_t r;
    asm("v_cvt_pk_bf16_f32 %0, %1, %2" : "=v"(r) : "v"(lo), "v"(hi));
    return r;
}
__device__ __forceinline__ float bf16lo_f(uint32_t u) { return __uint_as_float(u << 16); }
__device__ __forceinline__ float bf16hi_f(uint32_t u) { return __uint_as_float(u & 0xFFFF0000u); }
__device__ __forceinline__ unsigned short bf16_of(float v) {
    return (unsigned short)(cvt_pk_bf16(v, 0.f) & 0xFFFFu);
}

// ---------------------------------------------------------------------------
// Prep: bf16-transposed weights (identical to rounds 7-10).
// ---------------------------------------------------------------------------
__global__ void prep_kernel(
    const float* __restrict__ w1,  const float* __restrict__ b1,  const float* __restrict__ w2,
    const float* __restrict__ nw1, const float* __restrict__ nb1, const float* __restrict__ nw2,
    const float* __restrict__ mw1, const float* __restrict__ mb1, const float* __restrict__ mw2,
    unsigned short* __restrict__ w1x,  unsigned short* __restrict__ w2T,
    unsigned short* __restrict__ nw1x, unsigned short* __restrict__ nw2T,
    unsigned short* __restrict__ mw1x, unsigned short* __restrict__ mw2T)
{
    int t = blockIdx.x * 256 + threadIdx.x;
    if (t < 4096) {
        int j = t >> 6, k = t & 63;
        w2T [t] = bf16_of(w2 [k * HID + j]);
        nw2T[t] = bf16_of(nw2[k * HID + j]);
        mw2T[t] = bf16_of(mw2[k * HID + j]);
    }
    if (t < 512) {
        int j = t >> 3, k = t & 7;
        float ve = k == 0 ? w1[j] : k == 1 ? w1[HID + j] : k == 2 ? w1[2 * HID + j] : k == 3 ? b1[j] : 0.f;
        float vn = k == 0 ? nw1[j] : k == 1 ? nw1[HID + j] : k == 2 ? nb1[j] : 0.f;
        float vm = k == 0 ? mw1[j] : k == 1 ? mb1[j] : 0.f;
        w1x [t] = bf16_of(ve);
        nw1x[t] = bf16_of(vn);
        mw1x[t] = bf16_of(vm);
    }
}

// ---------------------------------------------------------------------------
// Edge v7: identical structure to round 10, but __launch_bounds__(256, 4):
// the unified VGPR+AGPR file must fit 4 waves/SIMD (<=128 regs total/wave).
// Live-set estimate ~120-125 -> should fit without spill (round 9's (256,6)
// capped at 85 and spilled catastrophically; round 10's (256,2) allowed the
// ~160-reg allocation that pinned occupancy at ~31% = 3 waves/SIMD).
// ---------------------------------------------------------------------------
__global__ __launch_bounds__(256, 4) void edge_mfma6_kernel(
    const float* __restrict__ nf, const float* __restrict__ ef,
    const int* __restrict__ src, const int* __restrict__ dst,
    const unsigned short* __restrict__ w1x, const unsigned short* __restrict__ w2T,
    const float* __restrict__ b2, const float* __restrict__ w3, const float* __restrict__ b3,
    uint2* __restrict__ recs, ull* __restrict__ offs,
    float* __restrict__ aggFb, int E, int B, int nbatch, int mode)
{
    __shared__ uint2 tile[4][2][16][16];   // [wave][set-in-phase][row][chunk] = 16 KB

    const int tid  = threadIdx.x;
    const int lane = tid & 63;
    const int wid  = tid >> 6;
    const int g    = lane >> 4;
    const int eL   = lane & 15;

    // ---- weights: once per block, kept in VGPRs ----
    FragU af1[4];
#pragma unroll
    for (int t = 0; t < 4; ++t) {
        uint4 q = *(const uint4*)&w1x[(t * 16 + eL) * 8];
        af1[t].q = (g == 0) ? q : make_uint4(0, 0, 0, 0);
    }
    FragU af2[4][2];
#pragma unroll
    for (int t = 0; t < 4; ++t)
#pragma unroll
        for (int h = 0; h < 2; ++h)
            af2[t][h].q = *(const uint4*)&w2T[(t * 16 + eL) * 64 + h * 32 + g * 8];

    f32x4 b2v4[4];
    uint32_t w3p[8];
#pragma unroll
    for (int t = 0; t < 4; ++t) {
        int j = t * 16 + g * 4;
        b2v4[t] = *(const f32x4*)&b2[j];
        f32x4 wv = *(const f32x4*)&w3[j];
        w3p[2 * t]     = cvt_pk_bf16(wv[0], wv[1]);
        w3p[2 * t + 1] = cvt_pk_bf16(wv[2], wv[3]);
    }
    const float b3c = b3[0];

    // ---- first batch loads ----
    int bi   = blockIdx.x;
    if (bi >= nbatch) return;
    int eidx = bi * 256 + tid;
    int ei   = eidx < E ? eidx : E - 1;
    int dcur = dst[ei];
    float a  = nf[src[ei]];
    float b  = nf[dcur];
    float c  = ef[ei];

    for (;;) {
        // ---- prefetch next batch indices (issued early, consumed late) ----
        const int nbi   = bi + gridDim.x;
        const bool hn   = nbi < nbatch;
        const int neidx = hn ? nbi * 256 + tid : eidx;
        const int nei   = neidx < E ? neidx : E - 1;
        const int ns    = src[nei];
        const int nd    = dst[nei];
        const float ncf = ef[nei];

        float na = 0.f, nb = 0.f;
        float mymsg = 0.f;

#pragma unroll
        for (int ph = 0; ph < 2; ++ph) {
            // ---- L1 phase for sets 2ph, 2ph+1 ----
#pragma unroll
            for (int ss = 0; ss < 2; ++ss) {
                const int s = 2 * ph + ss;
                float av = __shfl(a, s * 16 + eL);
                float bv = __shfl(b, s * 16 + eL);
                float cv = __shfl(c, s * 16 + eL);
                FragU bin;
                bin.u[0] = (g == 0) ? cvt_pk_bf16(av, bv) : 0u;
                bin.u[1] = (g == 0) ? cvt_pk_bf16(cv, 1.0f) : 0u;
                bin.u[2] = 0u; bin.u[3] = 0u;
#pragma unroll
                for (int t = 0; t < 4; ++t) {
                    f32x4 h4 = __builtin_amdgcn_mfma_f32_16x16x32_bf16(
                        af1[t].v, bin.v, (f32x4){0.f, 0.f, 0.f, 0.f}, 0, 0, 0);
                    uint32_t p0 = cvt_pk_bf16(fmaxf(h4[0], 0.f), fmaxf(h4[1], 0.f));
                    uint32_t p1 = cvt_pk_bf16(fmaxf(h4[2], 0.f), fmaxf(h4[3], 0.f));
                    tile[wid][ss][eL][(4 * t + g) ^ ((eL & 7) << 1)] = make_uint2(p0, p1);
                }
            }

            // ---- gathers for next batch: issue once, hidden under L2+phase1 ----
            if (ph == 0) {
                na = nf[ns];
                nb = nf[nd];
            }

            // ---- L2 phase for sets 2ph, 2ph+1 ----
#pragma unroll
            for (int ss = 0; ss < 2; ++ss) {
                const int s = 2 * ph + ss;
                const uint4* row = (const uint4*)&tile[wid][ss][eL][0];
                FragU bf0, bf1;
                bf0.q = row[(g)     ^ (eL & 7)];
                bf1.q = row[(4 + g) ^ (eL & 7)];

                float q0, q1, q2, q3;
                {
                    f32x4 ac = __builtin_amdgcn_mfma_f32_16x16x32_bf16(af2[0][0].v, bf0.v, b2v4[0], 0, 0, 0);
                    ac = __builtin_amdgcn_mfma_f32_16x16x32_bf16(af2[0][1].v, bf1.v, ac, 0, 0, 0);
                    q0 = fmaxf(ac[0], 0.f) * bf16lo_f(w3p[0]);
                    q0 = fmaf(fmaxf(ac[1], 0.f), bf16hi_f(w3p[0]), q0);
                    q0 = fmaf(fmaxf(ac[2], 0.f), bf16lo_f(w3p[1]), q0);
                    q0 = fmaf(fmaxf(ac[3], 0.f), bf16hi_f(w3p[1]), q0);
                }
                {
                    f32x4 ac = __builtin_amdgcn_mfma_f32_16x16x32_bf16(af2[1][0].v, bf0.v, b2v4[1], 0, 0, 0);
                    ac = __builtin_amdgcn_mfma_f32_16x16x32_bf16(af2[1][1].v, bf1.v, ac, 0, 0, 0);
                    q1 = fmaxf(ac[0], 0.f) * bf16lo_f(w3p[2]);
                    q1 = fmaf(fmaxf(ac[1], 0.f), bf16hi_f(w3p[2]), q1);
                    q1 = fmaf(fmaxf(ac[2], 0.f), bf16lo_f(w3p[3]), q1);
                    q1 = fmaf(fmaxf(ac[3], 0.f), bf16hi_f(w3p[3]), q1);
                }
                {
                    f32x4 ac = __builtin_amdgcn_mfma_f32_16x16x32_bf16(af2[2][0].v, bf0.v, b2v4[2], 0, 0, 0);
                    ac = __builtin_amdgcn_mfma_f32_16x16x32_bf16(af2[2][1].v, bf1.v, ac, 0, 0, 0);
                    q2 = fmaxf(ac[0], 0.f) * bf16lo_f(w3p[4]);
                    q2 = fmaf(fmaxf(ac[1], 0.f), bf16hi_f(w3p[4]), q2);
                    q2 = fmaf(fmaxf(ac[2], 0.f), bf16lo_f(w3p[5]), q2);
                    q2 = fmaf(fmaxf(ac[3], 0.f), bf16hi_f(w3p[5]), q2);
                }
                {
                    f32x4 ac = __builtin_amdgcn_mfma_f32_16x16x32_bf16(af2[3][0].v, bf0.v, b2v4[3], 0, 0, 0);
                    ac = __builtin_amdgcn_mfma_f32_16x16x32_bf16(af2[3][1].v, bf1.v, ac, 0, 0, 0);
                    q3 = fmaxf(ac[0], 0.f) * bf16lo_f(w3p[6]);
                    q3 = fmaf(fmaxf(ac[1], 0.f), bf16hi_f(w3p[6]), q3);
                    q3 = fmaf(fmaxf(ac[2], 0.f), bf16lo_f(w3p[7]), q3);
                    q3 = fmaf(fmaxf(ac[3], 0.f), bf16hi_f(w3p[7]), q3);
                }
                float p = (q0 + q1) + (q2 + q3);
                p += __shfl_xor(p, 16);
                p += __shfl_xor(p, 32);
                if (s == g) mymsg = p + b3c;
            }
        }

        const bool valid = eidx < E;

        if (mode == 1) {
            if (valid) atomicAdd(&aggFb[dcur], mymsg);
        } else {
            // ---- bucket append: coalesced wave-private, zero atomics ----
            const int bkt = dcur >> BKT_SHIFT;
            const ull lt = (1ull << lane) - 1;
            int myslot = 0;
            int off = 0;
            uint32_t pack_lo = 0, pack_hi = 0;
            for (int bb = 0; bb < B; ++bb) {
                if (bb < 4) pack_lo |= (uint32_t)off << (8 * bb);
                else        pack_hi |= (uint32_t)off << (8 * (bb - 4));
                ull m = __ballot(valid && bkt == bb);
                if (valid && bkt == bb) myslot = off + (int)__popcll(m & lt);
                off += (int)__popcll(m);
            }
            pack_hi |= (uint32_t)off << 24;

            const size_t wgl = (size_t)bi * 4 + wid;
            if (valid) recs[wgl * 64 + myslot] = make_uint2((uint32_t)dcur, __float_as_uint(mymsg));
            if (lane == 0) offs[wgl] = ((ull)pack_hi << 32) | (ull)pack_lo;
        }

        if (!hn) break;
        bi = nbi; eidx = neidx; ei = nei;
        a = na; b = nb; c = ncf; dcur = nd;
    }
}

// ---------------------------------------------------------------------------
// Phase B: block (b,c) accumulates bucket b's records from wave-chunk c into
// a 32KB LDS array (LDS atomics), then writes a dense partial plane.
// ---------------------------------------------------------------------------
__global__ __launch_bounds__(256) void bucket_accum_kernel(
    const uint2* __restrict__ recs, const ull* __restrict__ offs,
    float* __restrict__ partial, int NW, int B)
{
    __shared__ float acc[BKT_RANGE];

    const int b = blockIdx.x / CCHUNK;
    const int c = blockIdx.x % CCHUNK;

    for (int i = threadIdx.x; i < BKT_RANGE; i += 256) acc[i] = 0.f;
    __syncthreads();

    const int wpc = (NW + CCHUNK - 1) / CCHUNK;
    const int w0 = c * wpc;
    const int w1 = (w0 + wpc < NW) ? w0 + wpc : NW;
    const int nb = b + 1;
    const int base_node = b << BKT_SHIFT;

    for (int w = w0 + threadIdx.x; w < w1; w += 256) {
        ull ov = offs[w];
        uint32_t lo = (uint32_t)ov, hi = (uint32_t)(ov >> 32);
        int ob = (int)(((b  < 4) ? (lo >> (8 * b))  : (hi >> (8 * (b  - 4)))) & 0xFF);
        int oe = (int)(((nb < 4) ? (lo >> (8 * nb)) : (hi >> (8 * (nb - 4)))) & 0xFF);
        const uint2* rb = recs + (size_t)w * 64;
        for (int r = ob; r < oe; ++r) {
            uint2 rec = rb[r];
            atomicAdd(&acc[(int)rec.x - base_node], __uint_as_float(rec.y));
        }
    }
    __syncthreads();

    float* pb = partial + ((size_t)b * CCHUNK + c) * BKT_RANGE;
    for (int i = threadIdx.x; i < BKT_RANGE; i += 256) pb[i] = acc[i];
}

__global__ __launch_bounds__(256) void bucket_reduce_kernel(
    const float* __restrict__ partial, float* __restrict__ agg, int N)
{
    int n = blockIdx.x * 256 + threadIdx.x;
    if (n >= N) return;
    int b = n >> BKT_SHIFT, nl = n & (BKT_RANGE - 1);
    const float* p = partial + (size_t)b * CCHUNK * BKT_RANGE + nl;
    float s = 0.f;
#pragma unroll 8
    for (int c = 0; c < CCHUNK; ++c) s += p[(size_t)c * BKT_RANGE];
    agg[n] = s;
}

// ---------------------------------------------------------------------------
// Node v3: 4-wave blocks, 64 nodes per wave (unchanged from rounds 8-10).
// ---------------------------------------------------------------------------
__global__ __launch_bounds__(256, 2) void node_mfma3_kernel(
    const float* __restrict__ nf, const float* __restrict__ agg,
    const int* __restrict__ gid,
    const unsigned short* __restrict__ nw1x, const unsigned short* __restrict__ nw2T,
    const float* __restrict__ nb2, const float* __restrict__ nw3, const float* __restrict__ nb3,
    const unsigned short* __restrict__ mw1x, const unsigned short* __restrict__ mw2T,
    const float* __restrict__ mb2, const float* __restrict__ mw3, const float* __restrict__ mb3,
    float* __restrict__ rd, int N)
{
    __shared__ uint2 tile[4][4][16][16];   // 32 KB

    const int tid  = threadIdx.x;
    const int lane = tid & 63;
    const int wid  = tid >> 6;
    const int g    = lane >> 4;
    const int eL   = lane & 15;

    const int idx = blockIdx.x * 256 + tid;
    const int i   = idx < N ? idx : N - 1;
    const float x0 = nf[i];
    const float x1 = agg[i];
    const int   gg = gid[i];

    float myunf = 0.f, o = 0.f;

    // ================= MLP-N: [nf, agg] -> unf =================
    {
        FragU af1[4], af2[4][2];
        f32x4 b2v4[4]; uint32_t w3p[8];
#pragma unroll
        for (int t = 0; t < 4; ++t) {
            uint4 q = *(const uint4*)&nw1x[(t * 16 + eL) * 8];
            af1[t].q = (g == 0) ? q : make_uint4(0, 0, 0, 0);
#pragma unroll
            for (int h = 0; h < 2; ++h)
                af2[t][h].q = *(const uint4*)&nw2T[(t * 16 + eL) * 64 + h * 32 + g * 8];
            int j = t * 16 + g * 4;
            b2v4[t] = *(const f32x4*)&nb2[j];
            f32x4 wv = *(const f32x4*)&nw3[j];
            w3p[2 * t]     = cvt_pk_bf16(wv[0], wv[1]);
            w3p[2 * t + 1] = cvt_pk_bf16(wv[2], wv[3]);
        }

#pragma unroll
        for (int s = 0; s < 4; ++s) {
            float av = __shfl(x0, s * 16 + eL);
            float bv = __shfl(x1, s * 16 + eL);
            FragU bin;
            bin.u[0] = (g == 0) ? cvt_pk_bf16(av, bv) : 0u;
            bin.u[1] = (g == 0) ? cvt_pk_bf16(1.0f, 0.f) : 0u;
            bin.u[2] = 0u; bin.u[3] = 0u;
#pragma unroll
            for (int t = 0; t < 4; ++t) {
                f32x4 h4 = __builtin_amdgcn_mfma_f32_16x16x32_bf16(
                    af1[t].v, bin.v, (f32x4){0.f, 0.f, 0.f, 0.f}, 0, 0, 0);
                uint32_t p0 = cvt_pk_bf16(fmaxf(h4[0], 0.f), fmaxf(h4[1], 0.f));
                uint32_t p1 = cvt_pk_bf16(fmaxf(h4[2], 0.f), fmaxf(h4[3], 0.f));
                tile[wid][s][eL][(4 * t + g) ^ ((eL & 7) << 1)] = make_uint2(p0, p1);
            }
        }
#pragma unroll
        for (int s = 0; s < 4; ++s) {
            const uint4* row = (const uint4*)&tile[wid][s][eL][0];
            FragU bf0, bf1;
            bf0.q = row[(g)     ^ (eL & 7)];
            bf1.q = row[(4 + g) ^ (eL & 7)];
            float p = 0.f;
#pragma unroll
            for (int t = 0; t < 4; ++t) {
                f32x4 ac = __builtin_amdgcn_mfma_f32_16x16x32_bf16(af2[t][0].v, bf0.v, b2v4[t], 0, 0, 0);
                ac = __builtin_amdgcn_mfma_f32_16x16x32_bf16(af2[t][1].v, bf1.v, ac, 0, 0, 0);
                p = fmaf(fmaxf(ac[0], 0.f), bf16lo_f(w3p[2 * t]),     p);
                p = fmaf(fmaxf(ac[1], 0.f), bf16hi_f(w3p[2 * t]),     p);
                p = fmaf(fmaxf(ac[2], 0.f), bf16lo_f(w3p[2 * t + 1]), p);
                p = fmaf(fmaxf(ac[3], 0.f), bf16hi_f(w3p[2 * t + 1]), p);
            }
            p += __shfl_xor(p, 16);
            p += __shfl_xor(p, 32);
            if (s == g) myunf = p + nb3[0];
        }
    }

    // ================= MLP-M: unf -> o =================
    {
        FragU af1[4], af2[4][2];
        f32x4 b2v4[4]; uint32_t w3p[8];
#pragma unroll
        for (int t = 0; t < 4; ++t) {
            uint4 q = *(const uint4*)&mw1x[(t * 16 + eL) * 8];
            af1[t].q = (g == 0) ? q : make_uint4(0, 0, 0, 0);
#pragma unroll
            for (int h = 0; h < 2; ++h)
                af2[t][h].q = *(const uint4*)&mw2T[(t * 16 + eL) * 64 + h * 32 + g * 8];
            int j = t * 16 + g * 4;
            b2v4[t] = *(const f32x4*)&mb2[j];
            f32x4 wv = *(const f32x4*)&mw3[j];
            w3p[2 * t]     = cvt_pk_bf16(wv[0], wv[1]);
            w3p[2 * t + 1] = cvt_pk_bf16(wv[2], wv[3]);
        }

#pragma unroll
        for (int s = 0; s < 4; ++s) {
            float uv = __shfl(myunf, s * 16 + eL);
            FragU bin;
            bin.u[0] = (g == 0) ? cvt_pk_bf16(uv, 1.0f) : 0u;
            bin.u[1] = 0u; bin.u[2] = 0u; bin.u[3] = 0u;
#pragma unroll
            for (int t = 0; t < 4; ++t) {
                f32x4 h4 = __builtin_amdgcn_mfma_f32_16x16x32_bf16(
                    af1[t].v, bin.v, (f32x4){0.f, 0.f, 0.f, 0.f}, 0, 0, 0);
                uint32_t p0 = cvt_pk_bf16(fmaxf(h4[0], 0.f), fmaxf(h4[1], 0.f));
                uint32_t p1 = cvt_pk_bf16(fmaxf(h4[2], 0.f), fmaxf(h4[3], 0.f));
                tile[wid][s][eL][(4 * t + g) ^ ((eL & 7) << 1)] = make_uint2(p0, p1);
            }
        }
#pragma unroll
        for (int s = 0; s < 4; ++s) {
            const uint4* row = (const uint4*)&tile[wid][s][eL][0];
            FragU bf0, bf1;
            bf0.q = row[(g)     ^ (eL & 7)];
            bf1.q = row[(4 + g) ^ (eL & 7)];
            float p = 0.f;
#pragma unroll
            for (int t = 0; t < 4; ++t) {
                f32x4 ac = __builtin_amdgcn_mfma_f32_16x16x32_bf16(af2[t][0].v, bf0.v, b2v4[t], 0, 0, 0);
                ac = __builtin_amdgcn_mfma_f32_16x16x32_bf16(af2[t][1].v, bf1.v, ac, 0, 0, 0);
                p = fmaf(fmaxf(ac[0], 0.f), bf16lo_f(w3p[2 * t]),     p);
                p = fmaf(fmaxf(ac[1], 0.f), bf16hi_f(w3p[2 * t]),     p);
                p = fmaf(fmaxf(ac[2], 0.f), bf16lo_f(w3p[2 * t + 1]), p);
                p = fmaf(fmaxf(ac[3], 0.f), bf16hi_f(w3p[2 * t + 1]), p);
            }
            p += __shfl_xor(p, 16);
            p += __shfl_xor(p, 32);
            if (s == g) o = p + mb3[0];
        }
    }

    const float node_out = 1.0f / (1.0f + expf(-o));

    // ---- segmented reduction over sorted gid, one atomic per run tail ----
    {
        const bool ok = idx < N;
        float v = ok ? node_out : 0.0f;
        int ggv = gg;
#pragma unroll
        for (int d = 1; d < 64; d <<= 1) {
            float vup = __shfl_up(v, d);
            int   gup = __shfl_up(ggv, d);
            if (lane >= d && gup == ggv) v += vup;
        }
        int gdn = __shfl_down(ggv, 1);
        bool tail = (lane == 63) || (gdn != ggv);
        if (tail)
            atomicAdd(&rd[ggv], v);
    }
}

__global__ void readout_kernel(const float* __restrict__ rd,
                               float* __restrict__ out, int G)
{
    int g = blockIdx.x * blockDim.x + threadIdx.x;
    if (g < G) out[g] = 1.0f / (1.0f + expf(-rd[g]));
}

extern "C" void kernel_launch(void* const* d_in, const int* in_sizes, int n_in,
                              void* d_out, int out_size, void* d_ws, size_t ws_size,
                              hipStream_t stream)
{
    const float* nf  = (const float*)d_in[0];
    const float* ef  = (const float*)d_in[1];
    const int*   src = (const int*)  d_in[2];
    const int*   dst = (const int*)  d_in[3];
    const int*   gid = (const int*)  d_in[4];

    const float* e_w1 = (const float*)d_in[5];
    const float* e_b1 = (const float*)d_in[6];
    const float* e_w2 = (const float*)d_in[7];
    const float* e_b2 = (const float*)d_in[8];
    const float* e_w3 = (const float*)d_in[9];
    const float* e_b3 = (const float*)d_in[10];

    const float* n_w1 = (const float*)d_in[11];
    const float* n_b1 = (const float*)d_in[12];
    const float* n_w2 = (const float*)d_in[13];
    const float* n_b2 = (const float*)d_in[14];
    const float* n_w3 = (const float*)d_in[15];
    const float* n_b3 = (const float*)d_in[16];

    const float* m_w1 = (const float*)d_in[17];
    const float* m_b1 = (const float*)d_in[18];
    const float* m_w2 = (const float*)d_in[19];
    const float* m_b2 = (const float*)d_in[20];
    const float* m_w3 = (const float*)d_in[21];
    const float* m_b3 = (const float*)d_in[22];

    const int N = in_sizes[0];   // 50000
    const int E = in_sizes[2];   // 1600000
    const int G = out_size;      // 512

    const int nbatch = (E + 255) / 256;
    const int NW = (E + 63) / 64;
    const int B  = (N + BKT_RANGE - 1) / BKT_RANGE;

    size_t wts_b  = 32 * 1024;
    size_t recs_b = (size_t)NW * 64 * sizeof(uint2);
    size_t offs_b = (size_t)NW * sizeof(ull);
    size_t part_b = (size_t)B * CCHUNK * BKT_RANGE * sizeof(float);
    size_t need   = wts_b + recs_b + offs_b + part_b + ((size_t)N + G) * sizeof(float);
    bool bucketok = (B <= 8) && (need <= ws_size);

    char* wp = (char*)d_ws;
    unsigned short* w1x  = (unsigned short*)(wp);
    unsigned short* nw1x = (unsigned short*)(wp + 1024);
    unsigned short* mw1x = (unsigned short*)(wp + 2048);
    unsigned short* w2T  = (unsigned short*)(wp + 4096);
    unsigned short* nw2T = (unsigned short*)(wp + 4096 + 8192);
    unsigned short* mw2T = (unsigned short*)(wp + 4096 + 16384);

    float* out = (float*)d_out;

    prep_kernel<<<16, 256, 0, stream>>>(
        e_w1, e_b1, e_w2, n_w1, n_b1, n_w2, m_w1, m_b1, m_w2,
        w1x, w2T, nw1x, nw2T, mw1x, mw2T);

    int egrid = nbatch < 2048 ? nbatch : 2048;

    if (bucketok) {
        uint2* recs    = (uint2*)(wp + wts_b);
        ull*   offs    = (ull*)(wp + wts_b + recs_b);
        float* partial = (float*)(wp + wts_b + recs_b + offs_b);
        float* agg     = (float*)(wp + wts_b + recs_b + offs_b + part_b);
        float* rd      = agg + N;

        hipMemsetAsync(rd, 0, (size_t)G * sizeof(float), stream);

        edge_mfma6_kernel<<<egrid, 256, 0, stream>>>(
            nf, ef, src, dst, w1x, w2T, e_b2, e_w3, e_b3,
            recs, offs, nullptr, E, B, nbatch, 0);

        bucket_accum_kernel<<<B * CCHUNK, 256, 0, stream>>>(
            recs, offs, partial, NW, B);

        bucket_reduce_kernel<<<(N + 255) / 256, 256, 0, stream>>>(
            partial, agg, N);

        node_mfma3_kernel<<<(N + 255) / 256, 256, 0, stream>>>(
            nf, agg, gid,
            nw1x, nw2T, n_b2, n_w3, n_b3,
            mw1x, mw2T, m_b2, m_w3, m_b3,
            rd, N);

        readout_kernel<<<(G + 255) / 256, 256, 0, stream>>>(rd, out, G);
    } else {
        float* agg = (float*)(wp + wts_b);
        float* rd  = agg + N;

        hipMemsetAsync(agg, 0, ((size_t)N + G) * sizeof(float), stream);

        edge_mfma6_kernel<<<egrid, 256, 0, stream>>>(
            nf, ef, src, dst, w1x, w2T, e_b2, e_w3, e_b3,
            nullptr, nullptr, agg, E, B, nbatch, 1);

        node_mfma3_kernel<<<(N + 255) / 256, 256, 0, stream>>>(
            nf, agg, gid,
            nw1x, nw2T, n_b2, n_w3, n_b3,
            mw1x, mw2T, m_b2, m_w3, m_b3,
            rd, N);

        readout_kernel<<<(G + 255) / 256, 256, 0, stream>>>(rd, out, G);
    }
}

// Round 12
// 78.405 us; speedup vs baseline: 3.3532x; 1.0181x over previous
//
#include <hip/hip_runtime.h>
#include <math.h>

#define HID 64
#define BKT_SHIFT 13                 // 8192 nodes per bucket
#define BKT_RANGE 8192
#define CCHUNK 32                    // wave-chunks per bucket in phase B

typedef __attribute__((ext_vector_type(8))) short short8;
typedef __attribute__((ext_vector_type(4))) float f32x4;
typedef unsigned long long ull;

union FragU {
    uint4 q;
    short8 v;
    uint32_t u[4];
};

__device__ __forceinline__ uint32_t cvt_pk_bf16(float lo, float hi) {
    uint32_t r;
    asm("v_cvt_pk_bf16_f32 %0, %1, %2" : "=v"(r) : "v"(lo), "v"(hi));
    return r;
}
__device__ __forceinline__ unsigned short bf16_of(float v) {
    return (unsigned short)(cvt_pk_bf16(v, 0.f) & 0xFFFFu);
}

// ---------------------------------------------------------------------------
// Prep: bf16-transposed weights (identical to rounds 7-11).
// ---------------------------------------------------------------------------
__global__ void prep_kernel(
    const float* __restrict__ w1,  const float* __restrict__ b1,  const float* __restrict__ w2,
    const float* __restrict__ nw1, const float* __restrict__ nb1, const float* __restrict__ nw2,
    const float* __restrict__ mw1, const float* __restrict__ mb1, const float* __restrict__ mw2,
    unsigned short* __restrict__ w1x,  unsigned short* __restrict__ w2T,
    unsigned short* __restrict__ nw1x, unsigned short* __restrict__ nw2T,
    unsigned short* __restrict__ mw1x, unsigned short* __restrict__ mw2T)
{
    int t = blockIdx.x * 256 + threadIdx.x;
    if (t < 4096) {
        int j = t >> 6, k = t & 63;
        w2T [t] = bf16_of(w2 [k * HID + j]);
        nw2T[t] = bf16_of(nw2[k * HID + j]);
        mw2T[t] = bf16_of(mw2[k * HID + j]);
    }
    if (t < 512) {
        int j = t >> 3, k = t & 7;
        float ve = k == 0 ? w1[j] : k == 1 ? w1[HID + j] : k == 2 ? w1[2 * HID + j] : k == 3 ? b1[j] : 0.f;
        float vn = k == 0 ? nw1[j] : k == 1 ? nw1[HID + j] : k == 2 ? nb1[j] : 0.f;
        float vm = k == 0 ? mw1[j] : k == 1 ? mb1[j] : 0.f;
        w1x [t] = bf16_of(ve);
        nw1x[t] = bf16_of(vn);
        mw1x[t] = bf16_of(vm);
    }
}

// ---------------------------------------------------------------------------
// Edge v8: round-10 structure (persistent, 2-phase, 16 KB LDS, grid 2048).
// Micro-trims: w3 kept in f32 (kills 64 bf16-extract VALU ops/batch);
// s_setprio(1) around the L2 MFMA clusters (waves are independent, no
// barriers -> attn-like regime where setprio paid; not the GEMM-lockstep
// null).
// ---------------------------------------------------------------------------
__global__ __launch_bounds__(256, 2) void edge_mfma7_kernel(
    const float* __restrict__ nf, const float* __restrict__ ef,
    const int* __restrict__ src, const int* __restrict__ dst,
    const unsigned short* __restrict__ w1x, const unsigned short* __restrict__ w2T,
    const float* __restrict__ b2, const float* __restrict__ w3, const float* __restrict__ b3,
    uint2* __restrict__ recs, ull* __restrict__ offs,
    float* __restrict__ aggFb, int E, int B, int nbatch, int mode)
{
    __shared__ uint2 tile[4][2][16][16];   // 16 KB

    const int tid  = threadIdx.x;
    const int lane = tid & 63;
    const int wid  = tid >> 6;
    const int g    = lane >> 4;
    const int eL   = lane & 15;

    // ---- weights: once per block, kept in VGPRs ----
    FragU af1[4];
#pragma unroll
    for (int t = 0; t < 4; ++t) {
        uint4 q = *(const uint4*)&w1x[(t * 16 + eL) * 8];
        af1[t].q = (g == 0) ? q : make_uint4(0, 0, 0, 0);
    }
    FragU af2[4][2];
#pragma unroll
    for (int t = 0; t < 4; ++t)
#pragma unroll
        for (int h = 0; h < 2; ++h)
            af2[t][h].q = *(const uint4*)&w2T[(t * 16 + eL) * 64 + h * 32 + g * 8];

    f32x4 b2v4[4], w3v4[4];
#pragma unroll
    for (int t = 0; t < 4; ++t) {
        int j = t * 16 + g * 4;
        b2v4[t] = *(const f32x4*)&b2[j];
        w3v4[t] = *(const f32x4*)&w3[j];
    }
    const float b3c = b3[0];

    // ---- first batch loads ----
    int bi   = blockIdx.x;
    if (bi >= nbatch) return;
    int eidx = bi * 256 + tid;
    int ei   = eidx < E ? eidx : E - 1;
    int dcur = dst[ei];
    float a  = nf[src[ei]];
    float b  = nf[dcur];
    float c  = ef[ei];

    for (;;) {
        const int nbi   = bi + gridDim.x;
        const bool hn   = nbi < nbatch;
        const int neidx = hn ? nbi * 256 + tid : eidx;
        const int nei   = neidx < E ? neidx : E - 1;
        const int ns    = src[nei];
        const int nd    = dst[nei];
        const float ncf = ef[nei];

        float na = 0.f, nb = 0.f;
        float mymsg = 0.f;

#pragma unroll
        for (int ph = 0; ph < 2; ++ph) {
            // ---- L1 phase for sets 2ph, 2ph+1 ----
#pragma unroll
            for (int ss = 0; ss < 2; ++ss) {
                const int s = 2 * ph + ss;
                float av = __shfl(a, s * 16 + eL);
                float bv = __shfl(b, s * 16 + eL);
                float cv = __shfl(c, s * 16 + eL);
                FragU bin;
                bin.u[0] = (g == 0) ? cvt_pk_bf16(av, bv) : 0u;
                bin.u[1] = (g == 0) ? cvt_pk_bf16(cv, 1.0f) : 0u;
                bin.u[2] = 0u; bin.u[3] = 0u;
#pragma unroll
                for (int t = 0; t < 4; ++t) {
                    f32x4 h4 = __builtin_amdgcn_mfma_f32_16x16x32_bf16(
                        af1[t].v, bin.v, (f32x4){0.f, 0.f, 0.f, 0.f}, 0, 0, 0);
                    uint32_t p0 = cvt_pk_bf16(fmaxf(h4[0], 0.f), fmaxf(h4[1], 0.f));
                    uint32_t p1 = cvt_pk_bf16(fmaxf(h4[2], 0.f), fmaxf(h4[3], 0.f));
                    tile[wid][ss][eL][(4 * t + g) ^ ((eL & 7) << 1)] = make_uint2(p0, p1);
                }
            }

            if (ph == 0) {
                na = nf[ns];
                nb = nf[nd];
            }

            // ---- L2 phase for sets 2ph, 2ph+1 ----
            __builtin_amdgcn_s_setprio(1);
#pragma unroll
            for (int ss = 0; ss < 2; ++ss) {
                const int s = 2 * ph + ss;
                const uint4* row = (const uint4*)&tile[wid][ss][eL][0];
                FragU bf0, bf1;
                bf0.q = row[(g)     ^ (eL & 7)];
                bf1.q = row[(4 + g) ^ (eL & 7)];

                float q0, q1, q2, q3;
                {
                    f32x4 ac = __builtin_amdgcn_mfma_f32_16x16x32_bf16(af2[0][0].v, bf0.v, b2v4[0], 0, 0, 0);
                    ac = __builtin_amdgcn_mfma_f32_16x16x32_bf16(af2[0][1].v, bf1.v, ac, 0, 0, 0);
                    q0 = fmaxf(ac[0], 0.f) * w3v4[0][0];
                    q0 = fmaf(fmaxf(ac[1], 0.f), w3v4[0][1], q0);
                    q0 = fmaf(fmaxf(ac[2], 0.f), w3v4[0][2], q0);
                    q0 = fmaf(fmaxf(ac[3], 0.f), w3v4[0][3], q0);
                }
                {
                    f32x4 ac = __builtin_amdgcn_mfma_f32_16x16x32_bf16(af2[1][0].v, bf0.v, b2v4[1], 0, 0, 0);
                    ac = __builtin_amdgcn_mfma_f32_16x16x32_bf16(af2[1][1].v, bf1.v, ac, 0, 0, 0);
                    q1 = fmaxf(ac[0], 0.f) * w3v4[1][0];
                    q1 = fmaf(fmaxf(ac[1], 0.f), w3v4[1][1], q1);
                    q1 = fmaf(fmaxf(ac[2], 0.f), w3v4[1][2], q1);
                    q1 = fmaf(fmaxf(ac[3], 0.f), w3v4[1][3], q1);
                }
                {
                    f32x4 ac = __builtin_amdgcn_mfma_f32_16x16x32_bf16(af2[2][0].v, bf0.v, b2v4[2], 0, 0, 0);
                    ac = __builtin_amdgcn_mfma_f32_16x16x32_bf16(af2[2][1].v, bf1.v, ac, 0, 0, 0);
                    q2 = fmaxf(ac[0], 0.f) * w3v4[2][0];
                    q2 = fmaf(fmaxf(ac[1], 0.f), w3v4[2][1], q2);
                    q2 = fmaf(fmaxf(ac[2], 0.f), w3v4[2][2], q2);
                    q2 = fmaf(fmaxf(ac[3], 0.f), w3v4[2][3], q2);
                }
                {
                    f32x4 ac = __builtin_amdgcn_mfma_f32_16x16x32_bf16(af2[3][0].v, bf0.v, b2v4[3], 0, 0, 0);
                    ac = __builtin_amdgcn_mfma_f32_16x16x32_bf16(af2[3][1].v, bf1.v, ac, 0, 0, 0);
                    q3 = fmaxf(ac[0], 0.f) * w3v4[3][0];
                    q3 = fmaf(fmaxf(ac[1], 0.f), w3v4[3][1], q3);
                    q3 = fmaf(fmaxf(ac[2], 0.f), w3v4[3][2], q3);
                    q3 = fmaf(fmaxf(ac[3], 0.f), w3v4[3][3], q3);
                }
                float p = (q0 + q1) + (q2 + q3);
                p += __shfl_xor(p, 16);
                p += __shfl_xor(p, 32);
                if (s == g) mymsg = p + b3c;
            }
            __builtin_amdgcn_s_setprio(0);
        }

        const bool valid = eidx < E;

        if (mode == 1) {
            if (valid) atomicAdd(&aggFb[dcur], mymsg);
        } else {
            const int bkt = dcur >> BKT_SHIFT;
            const ull lt = (1ull << lane) - 1;
            int myslot = 0;
            int off = 0;
            uint32_t pack_lo = 0, pack_hi = 0;
            for (int bb = 0; bb < B; ++bb) {
                if (bb < 4) pack_lo |= (uint32_t)off << (8 * bb);
                else        pack_hi |= (uint32_t)off << (8 * (bb - 4));
                ull m = __ballot(valid && bkt == bb);
                if (valid && bkt == bb) myslot = off + (int)__popcll(m & lt);
                off += (int)__popcll(m);
            }
            pack_hi |= (uint32_t)off << 24;

            const size_t wgl = (size_t)bi * 4 + wid;
            if (valid) recs[wgl * 64 + myslot] = make_uint2((uint32_t)dcur, __float_as_uint(mymsg));
            if (lane == 0) offs[wgl] = ((ull)pack_hi << 32) | (ull)pack_lo;
        }

        if (!hn) break;
        bi = nbi; eidx = neidx; ei = nei;
        a = na; b = nb; c = ncf; dcur = nd;
    }
}

// ---------------------------------------------------------------------------
// Phase B: block (b,c) accumulates bucket b's records from wave-chunk c into
// a 32KB LDS array (LDS atomics), writes a dense partial plane. Block 0 also
// zeroes rd (replaces the separate memset dispatch; node runs after us).
// ---------------------------------------------------------------------------
__global__ __launch_bounds__(256) void bucket_accum_kernel(
    const uint2* __restrict__ recs, const ull* __restrict__ offs,
    float* __restrict__ partial, float* __restrict__ rd, int G, int NW, int B)
{
    __shared__ float acc[BKT_RANGE];

    const int b = blockIdx.x / CCHUNK;
    const int c = blockIdx.x % CCHUNK;

    if (blockIdx.x == 0)
        for (int i = threadIdx.x; i < G; i += 256) rd[i] = 0.f;

    for (int i = threadIdx.x; i < BKT_RANGE; i += 256) acc[i] = 0.f;
    __syncthreads();

    const int wpc = (NW + CCHUNK - 1) / CCHUNK;
    const int w0 = c * wpc;
    const int w1 = (w0 + wpc < NW) ? w0 + wpc : NW;
    const int nb = b + 1;
    const int base_node = b << BKT_SHIFT;

    for (int w = w0 + threadIdx.x; w < w1; w += 256) {
        ull ov = offs[w];
        uint32_t lo = (uint32_t)ov, hi = (uint32_t)(ov >> 32);
        int ob = (int)(((b  < 4) ? (lo >> (8 * b))  : (hi >> (8 * (b  - 4)))) & 0xFF);
        int oe = (int)(((nb < 4) ? (lo >> (8 * nb)) : (hi >> (8 * (nb - 4)))) & 0xFF);
        const uint2* rb = recs + (size_t)w * 64;
        for (int r = ob; r < oe; ++r) {
            uint2 rec = rb[r];
            atomicAdd(&acc[(int)rec.x - base_node], __uint_as_float(rec.y));
        }
    }
    __syncthreads();

    float* pb = partial + ((size_t)b * CCHUNK + c) * BKT_RANGE;
    for (int i = threadIdx.x; i < BKT_RANGE; i += 256) pb[i] = acc[i];
}

// ---------------------------------------------------------------------------
// Node v4: 4-wave blocks, 64 nodes per wave. bucket_reduce FUSED: x1 is the
// sum over the CCHUNK partial planes (coalesced per-plane reads), removing a
// kernel dispatch + the agg round-trip. nplanes==1 -> fallback agg path.
// ---------------------------------------------------------------------------
__global__ __launch_bounds__(256, 2) void node_mfma4_kernel(
    const float* __restrict__ nf, const float* __restrict__ partial,
    const float* __restrict__ aggFb, int nplanes,
    const int* __restrict__ gid,
    const unsigned short* __restrict__ nw1x, const unsigned short* __restrict__ nw2T,
    const float* __restrict__ nb2, const float* __restrict__ nw3, const float* __restrict__ nb3,
    const unsigned short* __restrict__ mw1x, const unsigned short* __restrict__ mw2T,
    const float* __restrict__ mb2, const float* __restrict__ mw3, const float* __restrict__ mb3,
    float* __restrict__ rd, int N)
{
    __shared__ uint2 tile[4][4][16][16];   // 32 KB

    const int tid  = threadIdx.x;
    const int lane = tid & 63;
    const int wid  = tid >> 6;
    const int g    = lane >> 4;
    const int eL   = lane & 15;

    const int idx = blockIdx.x * 256 + tid;
    const int i   = idx < N ? idx : N - 1;
    const float x0 = nf[i];
    const int   gg = gid[i];

    float x1;
    if (nplanes == 1) {
        x1 = aggFb[i];
    } else {
        int bb = i >> BKT_SHIFT, nl = i & (BKT_RANGE - 1);
        const float* p = partial + (size_t)bb * CCHUNK * BKT_RANGE + nl;
        x1 = 0.f;
#pragma unroll 8
        for (int c = 0; c < CCHUNK; ++c) x1 += p[(size_t)c * BKT_RANGE];
    }

    float myunf = 0.f, o = 0.f;

    // ================= MLP-N: [nf, agg] -> unf =================
    {
        FragU af1[4], af2[4][2];
        f32x4 b2v4[4], w3v4[4];
#pragma unroll
        for (int t = 0; t < 4; ++t) {
            uint4 q = *(const uint4*)&nw1x[(t * 16 + eL) * 8];
            af1[t].q = (g == 0) ? q : make_uint4(0, 0, 0, 0);
#pragma unroll
            for (int h = 0; h < 2; ++h)
                af2[t][h].q = *(const uint4*)&nw2T[(t * 16 + eL) * 64 + h * 32 + g * 8];
            int j = t * 16 + g * 4;
            b2v4[t] = *(const f32x4*)&nb2[j];
            w3v4[t] = *(const f32x4*)&nw3[j];
        }

#pragma unroll
        for (int s = 0; s < 4; ++s) {
            float av = __shfl(x0, s * 16 + eL);
            float bv = __shfl(x1, s * 16 + eL);
            FragU bin;
            bin.u[0] = (g == 0) ? cvt_pk_bf16(av, bv) : 0u;
            bin.u[1] = (g == 0) ? cvt_pk_bf16(1.0f, 0.f) : 0u;
            bin.u[2] = 0u; bin.u[3] = 0u;
#pragma unroll
            for (int t = 0; t < 4; ++t) {
                f32x4 h4 = __builtin_amdgcn_mfma_f32_16x16x32_bf16(
                    af1[t].v, bin.v, (f32x4){0.f, 0.f, 0.f, 0.f}, 0, 0, 0);
                uint32_t p0 = cvt_pk_bf16(fmaxf(h4[0], 0.f), fmaxf(h4[1], 0.f));
                uint32_t p1 = cvt_pk_bf16(fmaxf(h4[2], 0.f), fmaxf(h4[3], 0.f));
                tile[wid][s][eL][(4 * t + g) ^ ((eL & 7) << 1)] = make_uint2(p0, p1);
            }
        }
#pragma unroll
        for (int s = 0; s < 4; ++s) {
            const uint4* row = (const uint4*)&tile[wid][s][eL][0];
            FragU bf0, bf1;
            bf0.q = row[(g)     ^ (eL & 7)];
            bf1.q = row[(4 + g) ^ (eL & 7)];
            float p = 0.f;
#pragma unroll
            for (int t = 0; t < 4; ++t) {
                f32x4 ac = __builtin_amdgcn_mfma_f32_16x16x32_bf16(af2[t][0].v, bf0.v, b2v4[t], 0, 0, 0);
                ac = __builtin_amdgcn_mfma_f32_16x16x32_bf16(af2[t][1].v, bf1.v, ac, 0, 0, 0);
                p = fmaf(fmaxf(ac[0], 0.f), w3v4[t][0], p);
                p = fmaf(fmaxf(ac[1], 0.f), w3v4[t][1], p);
                p = fmaf(fmaxf(ac[2], 0.f), w3v4[t][2], p);
                p = fmaf(fmaxf(ac[3], 0.f), w3v4[t][3], p);
            }
            p += __shfl_xor(p, 16);
            p += __shfl_xor(p, 32);
            if (s == g) myunf = p + nb3[0];
        }
    }

    // ================= MLP-M: unf -> o =================
    {
        FragU af1[4], af2[4][2];
        f32x4 b2v4[4], w3v4[4];
#pragma unroll
        for (int t = 0; t < 4; ++t) {
            uint4 q = *(const uint4*)&mw1x[(t * 16 + eL) * 8];
            af1[t].q = (g == 0) ? q : make_uint4(0, 0, 0, 0);
#pragma unroll
            for (int h = 0; h < 2; ++h)
                af2[t][h].q = *(const uint4*)&mw2T[(t * 16 + eL) * 64 + h * 32 + g * 8];
            int j = t * 16 + g * 4;
            b2v4[t] = *(const f32x4*)&mb2[j];
            w3v4[t] = *(const f32x4*)&mw3[j];
        }

#pragma unroll
        for (int s = 0; s < 4; ++s) {
            float uv = __shfl(myunf, s * 16 + eL);
            FragU bin;
            bin.u[0] = (g == 0) ? cvt_pk_bf16(uv, 1.0f) : 0u;
            bin.u[1] = 0u; bin.u[2] = 0u; bin.u[3] = 0u;
#pragma unroll
            for (int t = 0; t < 4; ++t) {
                f32x4 h4 = __builtin_amdgcn_mfma_f32_16x16x32_bf16(
                    af1[t].v, bin.v, (f32x4){0.f, 0.f, 0.f, 0.f}, 0, 0, 0);
                uint32_t p0 = cvt_pk_bf16(fmaxf(h4[0], 0.f), fmaxf(h4[1], 0.f));
                uint32_t p1 = cvt_pk_bf16(fmaxf(h4[2], 0.f), fmaxf(h4[3], 0.f));
                tile[wid][s][eL][(4 * t + g) ^ ((eL & 7) << 1)] = make_uint2(p0, p1);
            }
        }
#pragma unroll
        for (int s = 0; s < 4; ++s) {
            const uint4* row = (const uint4*)&tile[wid][s][eL][0];
            FragU bf0, bf1;
            bf0.q = row[(g)     ^ (eL & 7)];
            bf1.q = row[(4 + g) ^ (eL & 7)];
            float p = 0.f;
#pragma unroll
            for (int t = 0; t < 4; ++t) {
                f32x4 ac = __builtin_amdgcn_mfma_f32_16x16x32_bf16(af2[t][0].v, bf0.v, b2v4[t], 0, 0, 0);
                ac = __builtin_amdgcn_mfma_f32_16x16x32_bf16(af2[t][1].v, bf1.v, ac, 0, 0, 0);
                p = fmaf(fmaxf(ac[0], 0.f), w3v4[t][0], p);
                p = fmaf(fmaxf(ac[1], 0.f), w3v4[t][1], p);
                p = fmaf(fmaxf(ac[2], 0.f), w3v4[t][2], p);
                p = fmaf(fmaxf(ac[3], 0.f), w3v4[t][3], p);
            }
            p += __shfl_xor(p, 16);
            p += __shfl_xor(p, 32);
            if (s == g) o = p + mb3[0];
        }
    }

    const float node_out = 1.0f / (1.0f + expf(-o));

    // ---- segmented reduction over sorted gid, one atomic per run tail ----
    {
        const bool ok = idx < N;
        float v = ok ? node_out : 0.0f;
        int ggv = gg;
#pragma unroll
        for (int d = 1; d < 64; d <<= 1) {
            float vup = __shfl_up(v, d);
            int   gup = __shfl_up(ggv, d);
            if (lane >= d && gup == ggv) v += vup;
        }
        int gdn = __shfl_down(ggv, 1);
        bool tail = (lane == 63) || (gdn != ggv);
        if (tail)
            atomicAdd(&rd[ggv], v);
    }
}

__global__ void readout_kernel(const float* __restrict__ rd,
                               float* __restrict__ out, int G)
{
    int g = blockIdx.x * blockDim.x + threadIdx.x;
    if (g < G) out[g] = 1.0f / (1.0f + expf(-rd[g]));
}

extern "C" void kernel_launch(void* const* d_in, const int* in_sizes, int n_in,
                              void* d_out, int out_size, void* d_ws, size_t ws_size,
                              hipStream_t stream)
{
    const float* nf  = (const float*)d_in[0];
    const float* ef  = (const float*)d_in[1];
    const int*   src = (const int*)  d_in[2];
    const int*   dst = (const int*)  d_in[3];
    const int*   gid = (const int*)  d_in[4];

    const float* e_w1 = (const float*)d_in[5];
    const float* e_b1 = (const float*)d_in[6];
    const float* e_w2 = (const float*)d_in[7];
    const float* e_b2 = (const float*)d_in[8];
    const float* e_w3 = (const float*)d_in[9];
    const float* e_b3 = (const float*)d_in[10];

    const float* n_w1 = (const float*)d_in[11];
    const float* n_b1 = (const float*)d_in[12];
    const float* n_w2 = (const float*)d_in[13];
    const float* n_b2 = (const float*)d_in[14];
    const float* n_w3 = (const float*)d_in[15];
    const float* n_b3 = (const float*)d_in[16];

    const float* m_w1 = (const float*)d_in[17];
    const float* m_b1 = (const float*)d_in[18];
    const float* m_w2 = (const float*)d_in[19];
    const float* m_b2 = (const float*)d_in[20];
    const float* m_w3 = (const float*)d_in[21];
    const float* m_b3 = (const float*)d_in[22];

    const int N = in_sizes[0];   // 50000
    const int E = in_sizes[2];   // 1600000
    const int G = out_size;      // 512

    const int nbatch = (E + 255) / 256;
    const int NW = (E + 63) / 64;
    const int B  = (N + BKT_RANGE - 1) / BKT_RANGE;

    size_t wts_b  = 32 * 1024;
    size_t recs_b = (size_t)NW * 64 * sizeof(uint2);
    size_t offs_b = (size_t)NW * sizeof(ull);
    size_t part_b = (size_t)B * CCHUNK * BKT_RANGE * sizeof(float);
    size_t need   = wts_b + recs_b + offs_b + part_b + (size_t)G * sizeof(float);
    bool bucketok = (B <= 8) && (need <= ws_size);

    char* wp = (char*)d_ws;
    unsigned short* w1x  = (unsigned short*)(wp);
    unsigned short* nw1x = (unsigned short*)(wp + 1024);
    unsigned short* mw1x = (unsigned short*)(wp + 2048);
    unsigned short* w2T  = (unsigned short*)(wp + 4096);
    unsigned short* nw2T = (unsigned short*)(wp + 4096 + 8192);
    unsigned short* mw2T = (unsigned short*)(wp + 4096 + 16384);

    float* out = (float*)d_out;

    prep_kernel<<<16, 256, 0, stream>>>(
        e_w1, e_b1, e_w2, n_w1, n_b1, n_w2, m_w1, m_b1, m_w2,
        w1x, w2T, nw1x, nw2T, mw1x, mw2T);

    int egrid = nbatch < 2048 ? nbatch : 2048;

    if (bucketok) {
        uint2* recs    = (uint2*)(wp + wts_b);
        ull*   offs    = (ull*)(wp + wts_b + recs_b);
        float* partial = (float*)(wp + wts_b + recs_b + offs_b);
        float* rd      = (float*)(wp + wts_b + recs_b + offs_b + part_b);

        edge_mfma7_kernel<<<egrid, 256, 0, stream>>>(
            nf, ef, src, dst, w1x, w2T, e_b2, e_w3, e_b3,
            recs, offs, nullptr, E, B, nbatch, 0);

        bucket_accum_kernel<<<B * CCHUNK, 256, 0, stream>>>(
            recs, offs, partial, rd, G, NW, B);

        node_mfma4_kernel<<<(N + 255) / 256, 256, 0, stream>>>(
            nf, partial, nullptr, CCHUNK, gid,
            nw1x, nw2T, n_b2, n_w3, n_b3,
            mw1x, mw2T, m_b2, m_w3, m_b3,
            rd, N);

        readout_kernel<<<(G + 255) / 256, 256, 0, stream>>>(rd, out, G);
    } else {
        float* agg = (float*)(wp + wts_b);
        float* rd  = agg + N;

        hipMemsetAsync(agg, 0, ((size_t)N + G) * sizeof(float), stream);

        edge_mfma7_kernel<<<egrid, 256, 0, stream>>>(
            nf, ef, src, dst, w1x, w2T, e_b2, e_w3, e_b3,
            nullptr, nullptr, agg, E, B, nbatch, 1);

        node_mfma4_kernel<<<(N + 255) / 256, 256, 0, stream>>>(
            nf, nullptr, agg, 1, gid,
            nw1x, nw2T, n_b2, n_w3, n_b3,
            mw1x, mw2T, m_b2, m_w3, m_b3,
            rd, N);

        readout_kernel<<<(G + 255) / 256, 256, 0, stream>>>(rd, out, G);
    }
}

// Round 13
// 72.128 us; speedup vs baseline: 3.6450x; 1.0870x over previous
//
#include <hip/hip_runtime.h>
#include <math.h>

#define HID 64
#define BKT_SHIFT 13                 // 8192 nodes per bucket
#define BKT_RANGE 8192
#define CCHUNK 32                    // wave-chunks per bucket in phase B

typedef __attribute__((ext_vector_type(8))) short short8;
typedef __attribute__((ext_vector_type(4))) float f32x4;
typedef unsigned long long ull;

union FragU {
    uint4 q;
    short8 v;
    uint32_t u[4];
};

__device__ __forceinline__ uint32_t cvt_pk_bf16(float lo, float hi) {
    uint32_t r;
    asm("v_cvt_pk_bf16_f32 %0, %1, %2" : "=v"(r) : "v"(lo), "v"(hi));
    return r;
}

// ---------------------------------------------------------------------------
// Edge v9: round-8 proven structure (persistent grid 1024, single L1 phase
// over 4 sets -> single L2 phase over 4 sets, 32 KB tile, launch_bounds
// (256,2), no setprio). Self-builds bf16 fragments from RAW f32 weights
// (kills the prep kernel + its serialization). Inputs packed once per batch
// (2 cvt) and distributed as packed words (8 bpermutes vs 12+8cvt).
// ---------------------------------------------------------------------------
__global__ __launch_bounds__(256, 2) void edge_mfma8_kernel(
    const float* __restrict__ nf, const float* __restrict__ ef,
    const int* __restrict__ src, const int* __restrict__ dst,
    const float* __restrict__ w1, const float* __restrict__ b1,
    const float* __restrict__ w2, const float* __restrict__ b2,
    const float* __restrict__ w3, const float* __restrict__ b3,
    uint2* __restrict__ recs, ull* __restrict__ offs,
    float* __restrict__ aggFb, int E, int B, int nbatch, int mode)
{
    __shared__ uint2 tile[4][4][16][16];   // 32 KB

    const int tid  = threadIdx.x;
    const int lane = tid & 63;
    const int wid  = tid >> 6;
    const int g    = lane >> 4;
    const int eL   = lane & 15;

    // ---- self-build weight fragments (once per block, coalesced f32 loads) ----
    FragU af1[4];
#pragma unroll
    for (int t = 0; t < 4; ++t) {
        int j = t * 16 + eL;
        uint32_t u0 = cvt_pk_bf16(w1[j], w1[HID + j]);
        uint32_t u1 = cvt_pk_bf16(w1[2 * HID + j], b1[j]);
        af1[t].u[0] = (g == 0) ? u0 : 0u;
        af1[t].u[1] = (g == 0) ? u1 : 0u;
        af1[t].u[2] = 0u; af1[t].u[3] = 0u;
    }
    FragU af2[4][2];
#pragma unroll
    for (int t = 0; t < 4; ++t)
#pragma unroll
        for (int h = 0; h < 2; ++h)
#pragma unroll
            for (int e2 = 0; e2 < 4; ++e2) {
                int k0 = h * 32 + g * 8 + 2 * e2;
                int j  = t * 16 + eL;
                af2[t][h].u[e2] = cvt_pk_bf16(w2[k0 * HID + j], w2[(k0 + 1) * HID + j]);
            }
    f32x4 b2v4[4], w3v4[4];
#pragma unroll
    for (int t = 0; t < 4; ++t) {
        int j = t * 16 + g * 4;
        b2v4[t] = *(const f32x4*)&b2[j];
        w3v4[t] = *(const f32x4*)&w3[j];
    }
    const float b3c = b3[0];

    // ---- first batch ----
    int bi   = blockIdx.x;
    if (bi >= nbatch) return;
    int eidx = bi * 256 + tid;
    int ei   = eidx < E ? eidx : E - 1;
    int dcur = dst[ei];
    float a  = nf[src[ei]];
    float b  = nf[dcur];
    float c  = ef[ei];
    uint32_t pkab = cvt_pk_bf16(a, b);
    uint32_t pkc1 = cvt_pk_bf16(c, 1.0f);

    for (;;) {
        // ---- prefetch next batch indices ----
        const int nbi   = bi + gridDim.x;
        const bool hn   = nbi < nbatch;
        const int neidx = hn ? nbi * 256 + tid : eidx;
        const int nei   = neidx < E ? neidx : E - 1;
        const int ns    = src[nei];
        const int nd    = dst[nei];
        const float ncf = ef[nei];

        // ---- L1 phase: 4 sets, 16 independent MFMAs ----
#pragma unroll
        for (int s = 0; s < 4; ++s) {
            int sel = s * 16 + eL;
            uint32_t u0 = (uint32_t)__shfl((int)pkab, sel);
            uint32_t u1 = (uint32_t)__shfl((int)pkc1, sel);
            FragU bin;
            bin.u[0] = (g == 0) ? u0 : 0u;
            bin.u[1] = (g == 0) ? u1 : 0u;
            bin.u[2] = 0u; bin.u[3] = 0u;
#pragma unroll
            for (int t = 0; t < 4; ++t) {
                f32x4 h4 = __builtin_amdgcn_mfma_f32_16x16x32_bf16(
                    af1[t].v, bin.v, (f32x4){0.f, 0.f, 0.f, 0.f}, 0, 0, 0);
                uint32_t p0 = cvt_pk_bf16(fmaxf(h4[0], 0.f), fmaxf(h4[1], 0.f));
                uint32_t p1 = cvt_pk_bf16(fmaxf(h4[2], 0.f), fmaxf(h4[3], 0.f));
                tile[wid][s][eL][(4 * t + g) ^ ((eL & 7) << 1)] = make_uint2(p0, p1);
            }
        }

        // ---- next batch gathers (hidden under L2 phase) ----
        const float na = nf[ns];
        const float nb = nf[nd];

        // ---- L2 phase: 4 sets x 8 MFMAs + epilogue (4 indep chains) ----
        float mymsg = 0.f;
#pragma unroll
        for (int s = 0; s < 4; ++s) {
            const uint4* row = (const uint4*)&tile[wid][s][eL][0];
            FragU bf0, bf1;
            bf0.q = row[(g)     ^ (eL & 7)];
            bf1.q = row[(4 + g) ^ (eL & 7)];

            float q0, q1, q2, q3;
            {
                f32x4 ac = __builtin_amdgcn_mfma_f32_16x16x32_bf16(af2[0][0].v, bf0.v, b2v4[0], 0, 0, 0);
                ac = __builtin_amdgcn_mfma_f32_16x16x32_bf16(af2[0][1].v, bf1.v, ac, 0, 0, 0);
                q0 = fmaxf(ac[0], 0.f) * w3v4[0][0];
                q0 = fmaf(fmaxf(ac[1], 0.f), w3v4[0][1], q0);
                q0 = fmaf(fmaxf(ac[2], 0.f), w3v4[0][2], q0);
                q0 = fmaf(fmaxf(ac[3], 0.f), w3v4[0][3], q0);
            }
            {
                f32x4 ac = __builtin_amdgcn_mfma_f32_16x16x32_bf16(af2[1][0].v, bf0.v, b2v4[1], 0, 0, 0);
                ac = __builtin_amdgcn_mfma_f32_16x16x32_bf16(af2[1][1].v, bf1.v, ac, 0, 0, 0);
                q1 = fmaxf(ac[0], 0.f) * w3v4[1][0];
                q1 = fmaf(fmaxf(ac[1], 0.f), w3v4[1][1], q1);
                q1 = fmaf(fmaxf(ac[2], 0.f), w3v4[1][2], q1);
                q1 = fmaf(fmaxf(ac[3], 0.f), w3v4[1][3], q1);
            }
            {
                f32x4 ac = __builtin_amdgcn_mfma_f32_16x16x32_bf16(af2[2][0].v, bf0.v, b2v4[2], 0, 0, 0);
                ac = __builtin_amdgcn_mfma_f32_16x16x32_bf16(af2[2][1].v, bf1.v, ac, 0, 0, 0);
                q2 = fmaxf(ac[0], 0.f) * w3v4[2][0];
                q2 = fmaf(fmaxf(ac[1], 0.f), w3v4[2][1], q2);
                q2 = fmaf(fmaxf(ac[2], 0.f), w3v4[2][2], q2);
                q2 = fmaf(fmaxf(ac[3], 0.f), w3v4[2][3], q2);
            }
            {
                f32x4 ac = __builtin_amdgcn_mfma_f32_16x16x32_bf16(af2[3][0].v, bf0.v, b2v4[3], 0, 0, 0);
                ac = __builtin_amdgcn_mfma_f32_16x16x32_bf16(af2[3][1].v, bf1.v, ac, 0, 0, 0);
                q3 = fmaxf(ac[0], 0.f) * w3v4[3][0];
                q3 = fmaf(fmaxf(ac[1], 0.f), w3v4[3][1], q3);
                q3 = fmaf(fmaxf(ac[2], 0.f), w3v4[3][2], q3);
                q3 = fmaf(fmaxf(ac[3], 0.f), w3v4[3][3], q3);
            }
            float p = (q0 + q1) + (q2 + q3);
            p += __shfl_xor(p, 16);
            p += __shfl_xor(p, 32);
            if (s == g) mymsg = p + b3c;
        }

        const bool valid = eidx < E;

        if (mode == 1) {
            if (valid) atomicAdd(&aggFb[dcur], mymsg);
        } else {
            // ---- bucket append: coalesced wave-private, zero atomics ----
            const int bkt = dcur >> BKT_SHIFT;
            const ull lt = (1ull << lane) - 1;
            int myslot = 0;
            int off = 0;
            uint32_t pack_lo = 0, pack_hi = 0;
            for (int bb = 0; bb < B; ++bb) {
                if (bb < 4) pack_lo |= (uint32_t)off << (8 * bb);
                else        pack_hi |= (uint32_t)off << (8 * (bb - 4));
                ull m = __ballot(valid && bkt == bb);
                if (valid && bkt == bb) myslot = off + (int)__popcll(m & lt);
                off += (int)__popcll(m);
            }
            pack_hi |= (uint32_t)off << 24;

            const size_t wgl = (size_t)bi * 4 + wid;
            if (valid) recs[wgl * 64 + myslot] = make_uint2((uint32_t)dcur, __float_as_uint(mymsg));
            if (lane == 0) offs[wgl] = ((ull)pack_hi << 32) | (ull)pack_lo;
        }

        if (!hn) break;
        bi = nbi; eidx = neidx;
        pkab = cvt_pk_bf16(na, nb);
        pkc1 = cvt_pk_bf16(ncf, 1.0f);
        dcur = nd;
    }
}

// ---------------------------------------------------------------------------
// Phase B: block (b,c) accumulates bucket b's records from wave-chunk c into
// a 32KB LDS array (LDS atomics), writes a dense partial plane. Block 0 also
// zeroes rd and the readout counter (node runs strictly after us in-stream).
// ---------------------------------------------------------------------------
__global__ __launch_bounds__(256) void bucket_accum_kernel(
    const uint2* __restrict__ recs, const ull* __restrict__ offs,
    float* __restrict__ partial, float* __restrict__ rd, unsigned* __restrict__ ctr,
    int G, int NW, int B)
{
    __shared__ float acc[BKT_RANGE];

    const int b = blockIdx.x / CCHUNK;
    const int c = blockIdx.x % CCHUNK;

    if (blockIdx.x == 0) {
        for (int i = threadIdx.x; i < G; i += 256) rd[i] = 0.f;
        if (threadIdx.x == 0) *ctr = 0u;
    }

    for (int i = threadIdx.x; i < BKT_RANGE; i += 256) acc[i] = 0.f;
    __syncthreads();

    const int wpc = (NW + CCHUNK - 1) / CCHUNK;
    const int w0 = c * wpc;
    const int w1 = (w0 + wpc < NW) ? w0 + wpc : NW;
    const int nb = b + 1;
    const int base_node = b << BKT_SHIFT;

    for (int w = w0 + threadIdx.x; w < w1; w += 256) {
        ull ov = offs[w];
        uint32_t lo = (uint32_t)ov, hi = (uint32_t)(ov >> 32);
        int ob = (int)(((b  < 4) ? (lo >> (8 * b))  : (hi >> (8 * (b  - 4)))) & 0xFF);
        int oe = (int)(((nb < 4) ? (lo >> (8 * nb)) : (hi >> (8 * (nb - 4)))) & 0xFF);
        const uint2* rb = recs + (size_t)w * 64;
        for (int r = ob; r < oe; ++r) {
            uint2 rec = rb[r];
            atomicAdd(&acc[(int)rec.x - base_node], __uint_as_float(rec.y));
        }
    }
    __syncthreads();

    float* pb = partial + ((size_t)b * CCHUNK + c) * BKT_RANGE;
    for (int i = threadIdx.x; i < BKT_RANGE; i += 256) pb[i] = acc[i];
}

// ---------------------------------------------------------------------------
// Node v5: 4-wave blocks, 64 nodes/wave, both MLPs on MFMA. Self-builds
// fragments from raw f32 weights (no prep). bucket_reduce fused (x1 = sum of
// CCHUNK planes). Readout FUSED: last block (atomic counter) computes
// out[g] = sigmoid(rd[g]) after a threadfence — removes a dispatch.
// ---------------------------------------------------------------------------
__global__ __launch_bounds__(256, 2) void node_mfma5_kernel(
    const float* __restrict__ nf, const float* __restrict__ partial,
    const float* __restrict__ aggFb, int nplanes,
    const int* __restrict__ gid,
    const float* __restrict__ nw1, const float* __restrict__ nb1,
    const float* __restrict__ nw2, const float* __restrict__ nb2,
    const float* __restrict__ nw3, const float* __restrict__ nb3,
    const float* __restrict__ mw1, const float* __restrict__ mb1,
    const float* __restrict__ mw2, const float* __restrict__ mb2,
    const float* __restrict__ mw3, const float* __restrict__ mb3,
    float* __restrict__ rd, float* __restrict__ outp, unsigned* __restrict__ ctr,
    int N, int G)
{
    __shared__ uint2 tile[4][4][16][16];   // 32 KB
    __shared__ int lastflag;

    const int tid  = threadIdx.x;
    const int lane = tid & 63;
    const int wid  = tid >> 6;
    const int g    = lane >> 4;
    const int eL   = lane & 15;

    const int idx = blockIdx.x * 256 + tid;
    const int i   = idx < N ? idx : N - 1;
    const float x0 = nf[i];
    const int   gg = gid[i];

    float x1;
    if (nplanes == 1) {
        x1 = aggFb[i];
    } else {
        int bb = i >> BKT_SHIFT, nl = i & (BKT_RANGE - 1);
        const float* p = partial + (size_t)bb * CCHUNK * BKT_RANGE + nl;
        x1 = 0.f;
#pragma unroll 8
        for (int c = 0; c < CCHUNK; ++c) x1 += p[(size_t)c * BKT_RANGE];
    }

    float myunf = 0.f, o = 0.f;

    // ================= MLP-N: [nf, agg] -> unf =================
    {
        FragU af1[4], af2[4][2];
        f32x4 b2v4[4], w3v4[4];
#pragma unroll
        for (int t = 0; t < 4; ++t) {
            int j = t * 16 + eL;
            uint32_t u0 = cvt_pk_bf16(nw1[j], nw1[HID + j]);
            uint32_t u1 = cvt_pk_bf16(nb1[j], 0.f);
            af1[t].u[0] = (g == 0) ? u0 : 0u;
            af1[t].u[1] = (g == 0) ? u1 : 0u;
            af1[t].u[2] = 0u; af1[t].u[3] = 0u;
#pragma unroll
            for (int h = 0; h < 2; ++h)
#pragma unroll
                for (int e2 = 0; e2 < 4; ++e2) {
                    int k0 = h * 32 + g * 8 + 2 * e2;
                    af2[t][h].u[e2] = cvt_pk_bf16(nw2[k0 * HID + j], nw2[(k0 + 1) * HID + j]);
                }
            int j4 = t * 16 + g * 4;
            b2v4[t] = *(const f32x4*)&nb2[j4];
            w3v4[t] = *(const f32x4*)&nw3[j4];
        }
        uint32_t pk01 = cvt_pk_bf16(x0, x1);
        uint32_t pkb  = cvt_pk_bf16(1.0f, 0.f);

#pragma unroll
        for (int s = 0; s < 4; ++s) {
            int sel = s * 16 + eL;
            uint32_t u0 = (uint32_t)__shfl((int)pk01, sel);
            FragU bin;
            bin.u[0] = (g == 0) ? u0 : 0u;
            bin.u[1] = (g == 0) ? pkb : 0u;
            bin.u[2] = 0u; bin.u[3] = 0u;
#pragma unroll
            for (int t = 0; t < 4; ++t) {
                f32x4 h4 = __builtin_amdgcn_mfma_f32_16x16x32_bf16(
                    af1[t].v, bin.v, (f32x4){0.f, 0.f, 0.f, 0.f}, 0, 0, 0);
                uint32_t p0 = cvt_pk_bf16(fmaxf(h4[0], 0.f), fmaxf(h4[1], 0.f));
                uint32_t p1 = cvt_pk_bf16(fmaxf(h4[2], 0.f), fmaxf(h4[3], 0.f));
                tile[wid][s][eL][(4 * t + g) ^ ((eL & 7) << 1)] = make_uint2(p0, p1);
            }
        }
#pragma unroll
        for (int s = 0; s < 4; ++s) {
            const uint4* row = (const uint4*)&tile[wid][s][eL][0];
            FragU bf0, bf1;
            bf0.q = row[(g)     ^ (eL & 7)];
            bf1.q = row[(4 + g) ^ (eL & 7)];
            float p = 0.f;
#pragma unroll
            for (int t = 0; t < 4; ++t) {
                f32x4 ac = __builtin_amdgcn_mfma_f32_16x16x32_bf16(af2[t][0].v, bf0.v, b2v4[t], 0, 0, 0);
                ac = __builtin_amdgcn_mfma_f32_16x16x32_bf16(af2[t][1].v, bf1.v, ac, 0, 0, 0);
                p = fmaf(fmaxf(ac[0], 0.f), w3v4[t][0], p);
                p = fmaf(fmaxf(ac[1], 0.f), w3v4[t][1], p);
                p = fmaf(fmaxf(ac[2], 0.f), w3v4[t][2], p);
                p = fmaf(fmaxf(ac[3], 0.f), w3v4[t][3], p);
            }
            p += __shfl_xor(p, 16);
            p += __shfl_xor(p, 32);
            if (s == g) myunf = p + nb3[0];
        }
    }

    // ================= MLP-M: unf -> o =================
    {
        FragU af1[4], af2[4][2];
        f32x4 b2v4[4], w3v4[4];
#pragma unroll
        for (int t = 0; t < 4; ++t) {
            int j = t * 16 + eL;
            uint32_t u0 = cvt_pk_bf16(mw1[j], mb1[j]);
            af1[t].u[0] = (g == 0) ? u0 : 0u;
            af1[t].u[1] = 0u; af1[t].u[2] = 0u; af1[t].u[3] = 0u;
#pragma unroll
            for (int h = 0; h < 2; ++h)
#pragma unroll
                for (int e2 = 0; e2 < 4; ++e2) {
                    int k0 = h * 32 + g * 8 + 2 * e2;
                    af2[t][h].u[e2] = cvt_pk_bf16(mw2[k0 * HID + j], mw2[(k0 + 1) * HID + j]);
                }
            int j4 = t * 16 + g * 4;
            b2v4[t] = *(const f32x4*)&mb2[j4];
            w3v4[t] = *(const f32x4*)&mw3[j4];
        }

#pragma unroll
        for (int s = 0; s < 4; ++s) {
            float uv = __shfl(myunf, s * 16 + eL);
            FragU bin;
            bin.u[0] = (g == 0) ? cvt_pk_bf16(uv, 1.0f) : 0u;
            bin.u[1] = 0u; bin.u[2] = 0u; bin.u[3] = 0u;
#pragma unroll
            for (int t = 0; t < 4; ++t) {
                f32x4 h4 = __builtin_amdgcn_mfma_f32_16x16x32_bf16(
                    af1[t].v, bin.v, (f32x4){0.f, 0.f, 0.f, 0.f}, 0, 0, 0);
                uint32_t p0 = cvt_pk_bf16(fmaxf(h4[0], 0.f), fmaxf(h4[1], 0.f));
                uint32_t p1 = cvt_pk_bf16(fmaxf(h4[2], 0.f), fmaxf(h4[3], 0.f));
                tile[wid][s][eL][(4 * t + g) ^ ((eL & 7) << 1)] = make_uint2(p0, p1);
            }
        }
#pragma unroll
        for (int s = 0; s < 4; ++s) {
            const uint4* row = (const uint4*)&tile[wid][s][eL][0];
            FragU bf0, bf1;
            bf0.q = row[(g)     ^ (eL & 7)];
            bf1.q = row[(4 + g) ^ (eL & 7)];
            float p = 0.f;
#pragma unroll
            for (int t = 0; t < 4; ++t) {
                f32x4 ac = __builtin_amdgcn_mfma_f32_16x16x32_bf16(af2[t][0].v, bf0.v, b2v4[t], 0, 0, 0);
                ac = __builtin_amdgcn_mfma_f32_16x16x32_bf16(af2[t][1].v, bf1.v, ac, 0, 0, 0);
                p = fmaf(fmaxf(ac[0], 0.f), w3v4[t][0], p);
                p = fmaf(fmaxf(ac[1], 0.f), w3v4[t][1], p);
                p = fmaf(fmaxf(ac[2], 0.f), w3v4[t][2], p);
                p = fmaf(fmaxf(ac[3], 0.f), w3v4[t][3], p);
            }
            p += __shfl_xor(p, 16);
            p += __shfl_xor(p, 32);
            if (s == g) o = p + mb3[0];
        }
    }

    const float node_out = 1.0f / (1.0f + expf(-o));

    // ---- segmented reduction over sorted gid, one atomic per run tail ----
    {
        const bool ok = idx < N;
        float v = ok ? node_out : 0.0f;
        int ggv = gg;
#pragma unroll
        for (int d = 1; d < 64; d <<= 1) {
            float vup = __shfl_up(v, d);
            int   gup = __shfl_up(ggv, d);
            if (lane >= d && gup == ggv) v += vup;
        }
        int gdn = __shfl_down(ggv, 1);
        bool tail = (lane == 63) || (gdn != ggv);
        if (tail)
            atomicAdd(&rd[ggv], v);
    }

    // ---- fused readout: last block applies sigmoid(rd) -> out ----
    if (ctr) {
        if (tid == 0) {
            __threadfence();
            unsigned v = atomicAdd(ctr, 1u);
            lastflag = (v == (unsigned)(gridDim.x - 1)) ? 1 : 0;
        }
        __syncthreads();
        if (lastflag) {
            __threadfence();
            for (int q = tid; q < G; q += 256)
                outp[q] = 1.0f / (1.0f + expf(-rd[q]));
        }
    }
}

__global__ void readout_kernel(const float* __restrict__ rd,
                               float* __restrict__ out, int G)
{
    int g = blockIdx.x * blockDim.x + threadIdx.x;
    if (g < G) out[g] = 1.0f / (1.0f + expf(-rd[g]));
}

extern "C" void kernel_launch(void* const* d_in, const int* in_sizes, int n_in,
                              void* d_out, int out_size, void* d_ws, size_t ws_size,
                              hipStream_t stream)
{
    const float* nf  = (const float*)d_in[0];
    const float* ef  = (const float*)d_in[1];
    const int*   src = (const int*)  d_in[2];
    const int*   dst = (const int*)  d_in[3];
    const int*   gid = (const int*)  d_in[4];

    const float* e_w1 = (const float*)d_in[5];
    const float* e_b1 = (const float*)d_in[6];
    const float* e_w2 = (const float*)d_in[7];
    const float* e_b2 = (const float*)d_in[8];
    const float* e_w3 = (const float*)d_in[9];
    const float* e_b3 = (const float*)d_in[10];

    const float* n_w1 = (const float*)d_in[11];
    const float* n_b1 = (const float*)d_in[12];
    const float* n_w2 = (const float*)d_in[13];
    const float* n_b2 = (const float*)d_in[14];
    const float* n_w3 = (const float*)d_in[15];
    const float* n_b3 = (const float*)d_in[16];

    const float* m_w1 = (const float*)d_in[17];
    const float* m_b1 = (const float*)d_in[18];
    const float* m_w2 = (const float*)d_in[19];
    const float* m_b2 = (const float*)d_in[20];
    const float* m_w3 = (const float*)d_in[21];
    const float* m_b3 = (const float*)d_in[22];

    const int N = in_sizes[0];   // 50000
    const int E = in_sizes[2];   // 1600000
    const int G = out_size;      // 512

    const int nbatch = (E + 255) / 256;
    const int NW = (E + 63) / 64;
    const int B  = (N + BKT_RANGE - 1) / BKT_RANGE;

    size_t recs_b = (size_t)NW * 64 * sizeof(uint2);
    size_t offs_b = (size_t)NW * sizeof(ull);
    size_t part_b = (size_t)B * CCHUNK * BKT_RANGE * sizeof(float);
    size_t need   = recs_b + offs_b + part_b + (size_t)G * sizeof(float) + 64;
    bool bucketok = (B <= 8) && (need <= ws_size);

    char* wp = (char*)d_ws;
    float* out = (float*)d_out;

    int egrid = nbatch < 1024 ? nbatch : 1024;

    if (bucketok) {
        uint2*    recs    = (uint2*)wp;
        ull*      offs    = (ull*)(wp + recs_b);
        float*    partial = (float*)(wp + recs_b + offs_b);
        float*    rd      = (float*)(wp + recs_b + offs_b + part_b);
        unsigned* ctr     = (unsigned*)(wp + recs_b + offs_b + part_b + (size_t)G * sizeof(float));

        edge_mfma8_kernel<<<egrid, 256, 0, stream>>>(
            nf, ef, src, dst, e_w1, e_b1, e_w2, e_b2, e_w3, e_b3,
            recs, offs, nullptr, E, B, nbatch, 0);

        bucket_accum_kernel<<<B * CCHUNK, 256, 0, stream>>>(
            recs, offs, partial, rd, ctr, G, NW, B);

        node_mfma5_kernel<<<(N + 255) / 256, 256, 0, stream>>>(
            nf, partial, nullptr, CCHUNK, gid,
            n_w1, n_b1, n_w2, n_b2, n_w3, n_b3,
            m_w1, m_b1, m_w2, m_b2, m_w3, m_b3,
            rd, out, ctr, N, G);
    } else {
        float* agg = (float*)wp;
        float* rd  = agg + N;

        hipMemsetAsync(agg, 0, ((size_t)N + G) * sizeof(float), stream);

        edge_mfma8_kernel<<<egrid, 256, 0, stream>>>(
            nf, ef, src, dst, e_w1, e_b1, e_w2, e_b2, e_w3, e_b3,
            nullptr, nullptr, agg, E, B, nbatch, 1);

        node_mfma5_kernel<<<(N + 255) / 256, 256, 0, stream>>>(
            nf, nullptr, agg, 1, gid,
            n_w1, n_b1, n_w2, n_b2, n_w3, n_b3,
            m_w1, m_b1, m_w2, m_b2, m_w3, m_b3,
            rd, out, nullptr, N, G);

        readout_kernel<<<(G + 255) / 256, 256, 0, stream>>>(rd, out, G);
    }
}